// Round 8
// baseline (2812.986 us; speedup 1.0000x reference)
//
#include <hip/hip_runtime.h>
#include <math.h>

#define BB 16
#define SS 96
#define WW 48
#define EE 300
#define HH 256
#define GG 1024   // 4H
#define DD 512    // 2H
#define NSEQ 1536 // B*S
#define NKCW 18   // word chunks: 10 x-chunks (K=320 padded) + 8 h-chunks (K=256)

typedef __attribute__((ext_vector_type(8))) short bf16x8;
typedef __attribute__((ext_vector_type(4))) float f32x4;
typedef unsigned short ushort_t;

__device__ __forceinline__ float sigf(float v){ return 1.0f/(1.0f+__expf(-v)); }
__device__ __forceinline__ float tanhf_fast(float v){ return 1.0f - 2.0f/(__expf(2.0f*v)+1.0f); }

__device__ __forceinline__ unsigned short f2bf(float f){
  union { float f; unsigned u; } v; v.f = f;
  unsigned u = v.u;
  u += 0x7FFFu + ((u>>16)&1u);   // RNE
  return (unsigned short)(u>>16);
}

// ============ conversions into MFMA-lane-linear layouts ============
// xT[grp 96][t 48][kc 10][lane 64][8]
__global__ __launch_bounds__(256) void k_cvt_x(const float* __restrict__ x, ushort_t* __restrict__ xT){
  int i = blockIdx.x*256 + threadIdx.x;        // 96*48*10*64 groups
  int l = i & 63;
  int q = i >> 6;
  int kc = q % 10; q /= 10;
  int t  = q % 48;
  int grp = q / 48;
  int row = grp*16 + (l & 15);
  int e = kc*32 + (l >> 4)*8;
  const float* src = x + ((size_t)row*WW + t)*EE + e;
  ushort_t* dst = xT + (size_t)i*8;
  #pragma unroll
  for (int d=0; d<8; d++) dst[d] = (e+d < EE) ? f2bf(src[d]) : 0;
}

// WU[dir][kc 18][nt 64][lane 64][8]: kc<10 from W (K=320 pad of 300), kc>=10 from U (K=256)
__global__ __launch_bounds__(256) void k_cvt_wu(
    const float* __restrict__ Wf, const float* __restrict__ Uf,
    const float* __restrict__ Wb_, const float* __restrict__ Ub_,
    ushort_t* __restrict__ WU){
  int i = blockIdx.x*256 + threadIdx.x;        // 2*18*64*64 groups
  int l = i & 63;
  int nt = (i >> 6) & 63;
  int kc = (i >> 12) % NKCW;
  int dir = i / (NKCW*4096);
  int n = nt*16 + (l & 15);
  int lq8 = (l >> 4)*8;
  ushort_t* dst = WU + (size_t)i*8;
  if (kc < 10){
    int e = kc*32 + lq8;
    const float* src = (dir ? Wb_ : Wf) + (size_t)n*EE + e;
    #pragma unroll
    for (int d=0; d<8; d++) dst[d] = (e+d < EE) ? f2bf(src[d]) : 0;
  } else {
    int e = (kc-10)*32 + lq8;
    const float* src = (dir ? Ub_ : Uf) + (size_t)n*HH + e;
    #pragma unroll
    for (int d=0; d<8; d++) dst[d] = f2bf(src[d]);
  }
}

// Bt[dir][kc K/32][nt 64][lane 64][8] from row-major [1024][K] (per dir)
__global__ __launch_bounds__(256) void k_cvt_gen(
    const float* __restrict__ A0, const float* __restrict__ A1,
    ushort_t* __restrict__ Bt, int K){
  int i = blockIdx.x*256 + threadIdx.x;        // 2*(K/32)*64*64 groups
  int l = i & 63;
  int nt = (i >> 6) & 63;
  int nk = K >> 5;
  int kc = (i >> 12) % nk;
  int dir = i / (nk*4096);
  int n = nt*16 + (l & 15);
  int e = kc*32 + (l >> 4)*8;
  const float* src = (dir ? A1 : A0) + (size_t)n*K + e;
  ushort_t* dst = Bt + (size_t)i*8;
  #pragma unroll
  for (int d=0; d<8; d++) dst[d] = f2bf(src[d]);
}

// zero the sync/exchange arena
__global__ __launch_bounds__(128) void k_zero(unsigned* __restrict__ p, int n){
  int i = blockIdx.x*128 + threadIdx.x;
  if (i < n) p[i] = 0u;
}

// ============ pre-GEMM: gates_x for the word level, TIME-SLICED ============
__global__ __launch_bounds__(512) void k_gxw(
    const ushort_t* __restrict__ xT,   // [96][48][10][64][8]
    const ushort_t* __restrict__ WU,   // [2][18][64][64][8] (kc<10 = W-part)
    const float* __restrict__ bf_, const float* __restrict__ bb_,
    float* __restrict__ gxwA, float* __restrict__ gxwB,
    int L, int ph)
{
  const int grp = blockIdx.x;
  const int t0l = blockIdx.y*4;        // local t within slice
  const int dir = blockIdx.z >> 1;
  const int jh  = blockIdx.z & 1;
  const int tid = threadIdx.x;
  const int ng = tid >> 6, lane = tid & 63;
  const int lm = lane & 15, lq = lane >> 4;
  const int jt = jh*8 + ng;            // 0..15
  const int jc = jt*16 + lm;           // 0..255

  const int tbase = dir ? (WW - (ph+1)*L) : (ph*L);   // global t = tbase + t0l + tt
  float* GxS = dir ? gxwB : gxwA;

  const ushort_t* WUD = WU + (size_t)dir*NKCW*4096*8;
  const float* bias = dir ? bb_ : bf_;
  float bias_v[4];
  #pragma unroll
  for (int g=0; g<4; g++) bias_v[g] = bias[g*256 + jc];

  const ushort_t* xg = xT + ((size_t)grp*48 + (tbase + t0l))*10*512;

  bf16x8 curB[4], nxtB[4], curA[4], nxtA[4];
  #pragma unroll
  for (int g=0; g<4; g++)
    curB[g] = *(const bf16x8*)(WUD + ((size_t)(g*16 + jt)*64 + lane)*8);
  #pragma unroll
  for (int tt=0; tt<4; tt++)
    curA[tt] = *(const bf16x8*)(xg + (size_t)tt*10*512 + lane*8);

  f32x4 acc[4][4];
  #pragma unroll
  for (int tt=0; tt<4; tt++)
    #pragma unroll
    for (int g=0; g<4; g++){ acc[tt][g][0]=0.f; acc[tt][g][1]=0.f; acc[tt][g][2]=0.f; acc[tt][g][3]=0.f; }

  #pragma unroll
  for (int kc=0; kc<10; kc++){
    if (kc < 9){
      const int k1 = kc+1;
      #pragma unroll
      for (int g=0; g<4; g++)
        nxtB[g] = *(const bf16x8*)(WUD + ((size_t)k1*4096 + (g*16 + jt)*64 + lane)*8);
      #pragma unroll
      for (int tt=0; tt<4; tt++)
        nxtA[tt] = *(const bf16x8*)(xg + (size_t)tt*10*512 + k1*512 + lane*8);
    }
    #pragma unroll
    for (int tt=0; tt<4; tt++)
      #pragma unroll
      for (int g=0; g<4; g++)
        acc[tt][g] = __builtin_amdgcn_mfma_f32_16x16x32_bf16(curA[tt], curB[g], acc[tt][g], 0,0,0);
    #pragma unroll
    for (int g=0; g<4; g++) curB[g] = nxtB[g];
    #pragma unroll
    for (int tt=0; tt<4; tt++) curA[tt] = nxtA[tt];
  }

  f32x4* GxV = (f32x4*)GxS;
  #pragma unroll
  for (int tt=0; tt<4; tt++)
    #pragma unroll
    for (int r=0; r<4; r++){
      f32x4 v;
      v[0] = acc[tt][0][r] + bias_v[0];
      v[1] = acc[tt][1][r] + bias_v[1];
      v[2] = acc[tt][2][r] + bias_v[2];
      v[3] = acc[tt][3][r] + bias_v[3];
      GxV[(((size_t)grp*L + (t0l+tt))*16 + lq*4 + r)*256 + jc] = v;
    }
}

// ============ word-level recurrent BiLSTM, U-only, PHASED ============
// R7 edit: Gxw reads hoisted to the TOP of each step (h-independent) so their
// HBM latency hides under the whole MFMA chain instead of serializing at the
// end of the step. 96 blocks <= 256 CUs -> +64 VGPR costs no occupancy.
__global__ __launch_bounds__(512) void k_word_u_phase(
    const float* __restrict__ gxwA, const float* __restrict__ gxwB,
    const ushort_t* __restrict__ WU,   // U chunks at [dir][10..17][..]
    float* __restrict__ maxacc,        // [1536][512]
    const int* __restrict__ slen,
    float* __restrict__ cstS,          // [96][512][16]
    float* __restrict__ mvvS,          // [96][512][16]
    ushort_t* __restrict__ hstS,       // [96][32][256]
    int L, int ph, int NPH)
{
  const int id = blockIdx.x;
  const int xcd = id & 7;
  const int dir = xcd & 1;
  const int bx = (xcd >> 1)*12 + (id >> 3);
  const int tid = threadIdx.x;
  const int ng = tid >> 6, lane = tid & 63;
  const int lm = lane & 15, lq = lane >> 4;
  const int jt0 = ng*32;

  __shared__ __align__(16) ushort_t hlds[2][32][264];
  for (int i = tid; i < 2*32*264/2; i += 512) ((unsigned*)hlds)[i] = 0u;
  __syncthreads();

  const ushort_t* UD = WU + (size_t)dir*NKCW*4096*8 + (size_t)10*4096*8;
  int ntb[4][2];
  #pragma unroll
  for (int g=0; g<4; g++)
    #pragma unroll
    for (int jt=0; jt<2; jt++) ntb[g][jt] = g*16 + ng*2 + jt;

  int slen_v[2][4];
  #pragma unroll
  for (int mh=0; mh<2; mh++)
    #pragma unroll
    for (int r=0; r<4; r++) slen_v[mh][r] = slen[bx*32 + mh*16 + lq*4 + r];

  float cst[2][2][4], mvv[2][2][4];
  if (ph == 0){
    #pragma unroll
    for (int mh=0; mh<2; mh++)
      #pragma unroll
      for (int jt=0; jt<2; jt++)
        #pragma unroll
        for (int r=0; r<4; r++){ cst[mh][jt][r]=0.f; mvv[mh][jt][r]=-1e30f; }
  } else {
    const float* cb = cstS + ((size_t)id*512 + tid)*16;
    const float* mb = mvvS + ((size_t)id*512 + tid)*16;
    #pragma unroll
    for (int mh=0; mh<2; mh++)
      #pragma unroll
      for (int jt=0; jt<2; jt++)
        #pragma unroll
        for (int r=0; r<4; r++){ cst[mh][jt][r]=cb[mh*8+jt*4+r]; mvv[mh][jt][r]=mb[mh*8+jt*4+r]; }
    const unsigned long long* hs = (const unsigned long long*)(hstS + (size_t)id*32*256);
    for (int i = tid; i < 2048; i += 512){
      int row = i >> 6, c8 = i & 63;
      *(unsigned long long*)&hlds[0][row][c8*4] = hs[i];
    }
  }

  const f32x4* GxS = (const f32x4*)(dir ? gxwB : gxwA);

  __syncthreads();
  int p = 0;

  for (int step=0; step<L; step++){
    const int t  = dir ? (WW-1 - ph*L - step) : (ph*L + step);   // global timestep
    const int tl = dir ? (L-1-step) : step;                      // local slice index

    // gates_x loads issued FIRST (h-independent) — hide under the MFMA chain
    f32x4 gxv[2][2][4];
    #pragma unroll
    for (int mh=0; mh<2; mh++)
      #pragma unroll
      for (int jt=0; jt<2; jt++)
        #pragma unroll
        for (int r=0; r<4; r++)
          gxv[mh][jt][r] = GxS[(((size_t)(bx*2+mh)*L + tl)*16 + lq*4 + r)*256 + jt0 + jt*16 + lm];

    bf16x8 curB[4][2], nxtB[4][2];
    bf16x8 curA0, curA1, nxtA0, nxtA1;
    #pragma unroll
    for (int g=0; g<4; g++)
      #pragma unroll
      for (int jt=0; jt<2; jt++)
        curB[g][jt] = *(const bf16x8*)(UD + ((size_t)ntb[g][jt]*64 + lane)*8);
    curA0 = *(const bf16x8*)&hlds[p][lm][lq*8];
    curA1 = *(const bf16x8*)&hlds[p][16+lm][lq*8];

    f32x4 acc[2][4][2];
    #pragma unroll
    for (int mh=0; mh<2; mh++)
      #pragma unroll
      for (int g=0; g<4; g++)
        #pragma unroll
        for (int jt=0; jt<2; jt++){ acc[mh][g][jt][0]=0.f; acc[mh][g][jt][1]=0.f; acc[mh][g][jt][2]=0.f; acc[mh][g][jt][3]=0.f; }

    #pragma unroll
    for (int kc=0; kc<8; kc++){
      if (kc < 7){
        const int k1 = kc+1;
        #pragma unroll
        for (int g=0; g<4; g++)
          #pragma unroll
          for (int jt=0; jt<2; jt++)
            nxtB[g][jt] = *(const bf16x8*)(UD + ((size_t)k1*4096 + ntb[g][jt]*64 + lane)*8);
        const int ko = k1*32 + lq*8;
        nxtA0 = *(const bf16x8*)&hlds[p][lm][ko];
        nxtA1 = *(const bf16x8*)&hlds[p][16+lm][ko];
      }
      #pragma unroll
      for (int g=0; g<4; g++)
        #pragma unroll
        for (int jt=0; jt<2; jt++){
          acc[0][g][jt] = __builtin_amdgcn_mfma_f32_16x16x32_bf16(curA0, curB[g][jt], acc[0][g][jt], 0,0,0);
          acc[1][g][jt] = __builtin_amdgcn_mfma_f32_16x16x32_bf16(curA1, curB[g][jt], acc[1][g][jt], 0,0,0);
        }
      #pragma unroll
      for (int g=0; g<4; g++)
        #pragma unroll
        for (int jt=0; jt<2; jt++) curB[g][jt] = nxtB[g][jt];
      curA0 = nxtA0; curA1 = nxtA1;
    }

    #pragma unroll
    for (int mh=0; mh<2; mh++)
      #pragma unroll
      for (int jt=0; jt<2; jt++)
        #pragma unroll
        for (int r=0; r<4; r++){
          float i_ = acc[mh][0][jt][r] + gxv[mh][jt][r][0];
          float f_ = acc[mh][1][jt][r] + gxv[mh][jt][r][1];
          float g_ = acc[mh][2][jt][r] + gxv[mh][jt][r][2];
          float o_ = acc[mh][3][jt][r] + gxv[mh][jt][r][3];
          float cn = sigf(f_)*cst[mh][jt][r] + sigf(i_)*tanhf_fast(g_);
          float hn = sigf(o_)*tanhf_fast(cn);
          cst[mh][jt][r] = cn;
          if (t < slen_v[mh][r]) mvv[mh][jt][r] = fmaxf(mvv[mh][jt][r], hn);
          hlds[1-p][mh*16 + lq*4 + r][jt0 + jt*16 + lm] = f2bf(hn);
        }
    __syncthreads();
    p ^= 1;
  }

  if (ph < NPH-1){
    float* cb = cstS + ((size_t)id*512 + tid)*16;
    float* mb = mvvS + ((size_t)id*512 + tid)*16;
    #pragma unroll
    for (int mh=0; mh<2; mh++)
      #pragma unroll
      for (int jt=0; jt<2; jt++)
        #pragma unroll
        for (int r=0; r<4; r++){ cb[mh*8+jt*4+r]=cst[mh][jt][r]; mb[mh*8+jt*4+r]=mvv[mh][jt][r]; }
    unsigned long long* hsv = (unsigned long long*)(hstS + (size_t)id*32*256);
    for (int i = tid; i < 2048; i += 512){
      int row = i >> 6, c8 = i & 63;
      hsv[i] = *(const unsigned long long*)&hlds[0][row][c8*4];
    }
  } else {
    #pragma unroll
    for (int mh=0; mh<2; mh++)
      #pragma unroll
      for (int jt=0; jt<2; jt++)
        #pragma unroll
        for (int r=0; r<4; r++)
          maxacc[(size_t)(bx*32 + mh*16 + lq*4 + r)*DD + dir*HH + jt0 + jt*16 + lm] = mvv[mh][jt][r];
  }
}

// ============ word-level persistent BiLSTM — FALLBACK (ws too small) ============
__global__ __launch_bounds__(512) __attribute__((amdgpu_waves_per_eu(2, 2))) void k_word_persist_full(
    const ushort_t* __restrict__ xT,
    const ushort_t* __restrict__ WU,
    const float* __restrict__ bf_, const float* __restrict__ bb_,
    float* __restrict__ maxacc,
    const int* __restrict__ slen)
{
  const int id = blockIdx.x;
  const int xcd = id & 7;
  const int dir = xcd & 1;
  const int bx = (xcd >> 1)*12 + (id >> 3);
  const int tid = threadIdx.x;
  const int ng = tid >> 6, lane = tid & 63;
  const int lm = lane & 15, lq = lane >> 4;
  const int jt0 = ng*32;

  __shared__ __align__(16) ushort_t hlds[2][32][264];
  for (int i = tid; i < 2*32*264/2; i += 512) ((unsigned*)hlds)[i] = 0u;

  const ushort_t* WUD = WU + (size_t)dir*NKCW*4096*8;
  int ntb[4][2];
  #pragma unroll
  for (int g=0; g<4; g++)
    #pragma unroll
    for (int jt=0; jt<2; jt++) ntb[g][jt] = g*16 + ng*2 + jt;

  const float* bias = dir ? bb_ : bf_;
  float bias_v[4][2];
  #pragma unroll
  for (int g=0; g<4; g++)
    #pragma unroll
    for (int jt=0; jt<2; jt++) bias_v[g][jt] = bias[g*256 + jt0 + jt*16 + lm];

  int slen_v[2][4];
  #pragma unroll
  for (int mh=0; mh<2; mh++)
    #pragma unroll
    for (int r=0; r<4; r++) slen_v[mh][r] = slen[bx*32 + mh*16 + lq*4 + r];

  float cst[2][2][4], mvv[2][2][4];
  #pragma unroll
  for (int mh=0; mh<2; mh++)
    #pragma unroll
    for (int jt=0; jt<2; jt++)
      #pragma unroll
      for (int r=0; r<4; r++){ cst[mh][jt][r]=0.f; mvv[mh][jt][r]=-1e30f; }

  const ushort_t* xg0 = xT + (size_t)(bx*2+0)*48*10*512;
  const ushort_t* xg1 = xT + (size_t)(bx*2+1)*48*10*512;

  __syncthreads();
  int p = 0;

  for (int step=0; step<WW; step++){
    const int t = dir ? (WW-1-step) : step;
    const size_t xoff = (size_t)t*10*512 + lane*8;

    bf16x8 curB[4][2], nxtB[4][2];
    bf16x8 curA0, curA1, nxtA0, nxtA1;
    #pragma unroll
    for (int g=0; g<4; g++)
      #pragma unroll
      for (int jt=0; jt<2; jt++)
        curB[g][jt] = *(const bf16x8*)(WUD + ((size_t)ntb[g][jt]*64 + lane)*8);
    curA0 = *(const bf16x8*)(xg0 + xoff);
    curA1 = *(const bf16x8*)(xg1 + xoff);

    f32x4 acc[2][4][2];
    #pragma unroll
    for (int mh=0; mh<2; mh++)
      #pragma unroll
      for (int g=0; g<4; g++)
        #pragma unroll
        for (int jt=0; jt<2; jt++){ acc[mh][g][jt][0]=0.f; acc[mh][g][jt][1]=0.f; acc[mh][g][jt][2]=0.f; acc[mh][g][jt][3]=0.f; }

    #pragma unroll
    for (int kc=0; kc<NKCW; kc++){
      if (kc < NKCW-1){
        const int k1 = kc+1;
        #pragma unroll
        for (int g=0; g<4; g++)
          #pragma unroll
          for (int jt=0; jt<2; jt++)
            nxtB[g][jt] = *(const bf16x8*)(WUD + ((size_t)k1*4096 + ntb[g][jt]*64 + lane)*8);
        if (k1 < 10){
          nxtA0 = *(const bf16x8*)(xg0 + xoff + k1*512);
          nxtA1 = *(const bf16x8*)(xg1 + xoff + k1*512);
        } else {
          const int ko = (k1-10)*32 + lq*8;
          nxtA0 = *(const bf16x8*)&hlds[p][lm][ko];
          nxtA1 = *(const bf16x8*)&hlds[p][16+lm][ko];
        }
      }
      #pragma unroll
      for (int g=0; g<4; g++)
        #pragma unroll
        for (int jt=0; jt<2; jt++){
          acc[0][g][jt] = __builtin_amdgcn_mfma_f32_16x16x32_bf16(curA0, curB[g][jt], acc[0][g][jt], 0,0,0);
          acc[1][g][jt] = __builtin_amdgcn_mfma_f32_16x16x32_bf16(curA1, curB[g][jt], acc[1][g][jt], 0,0,0);
        }
      #pragma unroll
      for (int g=0; g<4; g++)
        #pragma unroll
        for (int jt=0; jt<2; jt++) curB[g][jt] = nxtB[g][jt];
      curA0 = nxtA0; curA1 = nxtA1;
    }

    #pragma unroll
    for (int mh=0; mh<2; mh++)
      #pragma unroll
      for (int jt=0; jt<2; jt++)
        #pragma unroll
        for (int r=0; r<4; r++){
          float i_ = acc[mh][0][jt][r] + bias_v[0][jt];
          float f_ = acc[mh][1][jt][r] + bias_v[1][jt];
          float g_ = acc[mh][2][jt][r] + bias_v[2][jt];
          float o_ = acc[mh][3][jt][r] + bias_v[3][jt];
          float cn = sigf(f_)*cst[mh][jt][r] + sigf(i_)*tanhf_fast(g_);
          float hn = sigf(o_)*tanhf_fast(cn);
          cst[mh][jt][r] = cn;
          if (t < slen_v[mh][r]) mvv[mh][jt][r] = fmaxf(mvv[mh][jt][r], hn);
          hlds[1-p][mh*16 + lq*4 + r][jt0 + jt*16 + lm] = f2bf(hn);
        }
    __syncthreads();
    p ^= 1;
  }
  #pragma unroll
  for (int mh=0; mh<2; mh++)
    #pragma unroll
    for (int jt=0; jt<2; jt++)
      #pragma unroll
      for (int r=0; r<4; r++)
        maxacc[(size_t)(bx*32 + mh*16 + lq*4 + r)*DD + dir*HH + jt0 + jt*16 + lm] = mvv[mh][jt][r];
}

// ============ maxpool mask -> bf16 pooled ============
__global__ __launch_bounds__(256) void k_pool_maskb(
    const float* __restrict__ maxacc, ushort_t* __restrict__ pooled_bf, const int* __restrict__ dl)
{
  int i = blockIdx.x*256 + threadIdx.x;       // NSEQ*DD
  int m = i / DD; int b = m / SS; int s = m % SS;
  pooled_bf[i] = (s < dl[b]) ? f2bf(maxacc[i]) : 0;
}

// ============ bf16 GEMM: C[z][1536xGG] = A[1536xK] @ B[z] + bias (B lane-linear) ============
__global__ __launch_bounds__(256) void k_gemm_bf(
    const ushort_t* __restrict__ A,
    const ushort_t* __restrict__ Bt,      // [2][K/32][64][64][8]
    const float* __restrict__ bias0, const float* __restrict__ bias1,
    float* __restrict__ C,                // [2][NSEQ][GG]
    int K)
{
  const int z = blockIdx.z;
  const int nk = K >> 5;
  const ushort_t* BD = Bt + (size_t)z*nk*4096*8;
  const float* bias = z ? bias1 : bias0;
  float* Cz = C + (size_t)z*NSEQ*GG;

  const int tid = threadIdx.x;
  const int w = tid >> 6, lane = tid & 63;
  const int lm = lane & 15, lq = lane >> 4;
  const int m0 = blockIdx.x*64 + w*16, nt0 = blockIdx.y*8;

  const ushort_t* arow = A + (size_t)(m0+lm)*K + lq*8;

  f32x4 acc[8];
  #pragma unroll
  for (int j=0; j<8; j++){ acc[j][0]=0.f; acc[j][1]=0.f; acc[j][2]=0.f; acc[j][3]=0.f; }

  #pragma unroll 4
  for (int kc=0; kc<nk; kc++){
    bf16x8 a = *(const bf16x8*)(arow + kc*32);
    #pragma unroll
    for (int j=0; j<8; j++){
      bf16x8 b = *(const bf16x8*)(BD + ((size_t)kc*4096 + (nt0+j)*64 + lane)*8);
      acc[j] = __builtin_amdgcn_mfma_f32_16x16x32_bf16(a, b, acc[j], 0,0,0);
    }
  }
  #pragma unroll
  for (int j=0; j<8; j++){
    int n = (nt0+j)*16 + lm;
    float bv = bias[n];
    #pragma unroll
    for (int r=0; r<4; r++)
      Cz[(size_t)(m0 + lq*4 + r)*GG + n] = acc[j][r] + bv;
  }
}

// ============ sentence-level LSTM, PARALLEL — sync v3: XCD-LOCAL placement ============
// R7 post-mortem: packed publish + per-producer flags changed transaction count
// 4x with NO timing effect -> the chain is agent-scope ROUND-TRIP LATENCY.
// With dir = blockIdx>>3 the 8 blocks of a dir landed on 8 DIFFERENT XCDs
// (id&7 round-robin), forcing every flag/h crossing through L3/fabric.
// v3: launch 128 blocks; xcd=id&7, slot=id>>3; only xcd<2 && slot<8 work
// (dir = xcd) -> all 8 blocks of a dir on ONE XCD; agent traffic can be
// served by that XCD's L2. 112 blocks exit immediately (free CUs abound).
// Also: st padded [16][36] (72B stride, kills the 8-way bank conflict v2
// introduced), relaxed spin + single acquire re-read (acquire-per-poll paid
// an invalidate every iteration). Protocol and numerics unchanged.
__global__ __launch_bounds__(128) void k_sstep_par(
    const float* __restrict__ Gx,     // [2][1536][1024], bias included
    const ushort_t* __restrict__ Ut,  // [2][8][64][64][8]
    float* __restrict__ outseq,       // [16][96][512]
    ushort_t* __restrict__ hbuf,      // [2 parity][2 dir][16 doc][256] bf16, pre-zeroed
    unsigned* __restrict__ flags,     // [2 dir][96 step][8 producer], pre-zeroed
    const int* __restrict__ dl, int mask_out)
{
  const int xcd  = blockIdx.x & 7;
  const int slot = blockIdx.x >> 3;
  if (xcd >= 2 || slot >= 8) return;   // 16 working blocks: dir0 on XCD0, dir1 on XCD1
  const int dir = xcd;
  const int ns  = slot;
  const int tid = threadIdx.x;
  const int jt  = tid >> 6;
  const int lane = tid & 63, lm = lane & 15, lq = lane >> 4;

  __shared__ __align__(16) ushort_t Ul[8][4][2][64][8];   // 64 KB
  __shared__ __align__(16) ushort_t st[16][36];           // own h-slice staging (padded, conflict-free)

  {
    const ushort_t* UD = Ut + (size_t)dir*8*4096*8;
    for (int v = tid; v < 4096; v += 128){
      int lane_v = v & 63;
      int q = v >> 6;
      int jv = q & 1, gq = (q >> 1) & 3, kcv = q >> 3;
      const uint4* src = (const uint4*)(UD + ((size_t)kcv*4096 + (gq*16 + ns*2 + jv)*64 + lane_v)*8);
      ((uint4*)Ul)[v] = *src;
    }
  }
  for (int i = tid; i < 16*36/2; i += 128) ((unsigned*)st)[i] = 0u;

  int dl_v[4];
  #pragma unroll
  for (int r=0; r<4; r++) dl_v[r] = dl[lq*4 + r];

  float cst[4];
  #pragma unroll
  for (int r=0; r<4; r++) cst[r] = 0.f;

  unsigned* flg = flags + (size_t)dir*SS*8;
  const float* GxD = Gx + (size_t)dir*NSEQ*GG;
  ushort_t* hb0 = hbuf + (size_t)dir*16*256;
  ushort_t* hb1 = hbuf + (size_t)(2+dir)*16*256;
  const int j  = ns*32 + jt*16 + lm;    // global j-dim
  const int jl = jt*16 + lm;            // local j within slice

  __syncthreads();
  int p = 0;

  for (int step=0; step<SS; step++){
    const int t = dir ? (SS-1-step) : step;

    // Gx loads first — independent of h, hide under the wait
    float gx[4][4];
    #pragma unroll
    for (int g=0; g<4; g++)
      #pragma unroll
      for (int r=0; r<4; r++)
        gx[g][r] = GxD[((size_t)(lq*4+r)*SS + t)*GG + g*256 + j];

    // wait: 8 lanes relaxed-poll 8 per-producer flags; one acquire re-read at exit
    if (step > 0){
      if (tid < 8){
        const unsigned* f = &flg[(size_t)(step-1)*8 + tid];
        while (__hip_atomic_load(f, __ATOMIC_RELAXED, __HIP_MEMORY_SCOPE_AGENT) == 0u) {}
        (void)__hip_atomic_load(f, __ATOMIC_ACQUIRE, __HIP_MEMORY_SCOPE_AGENT);
      }
      __syncthreads();
    }
    ushort_t* hcur = p ? hb1 : hb0;
    ushort_t* hnxt = p ? hb0 : hb1;

    // A-frags: own chunk from LDS staging, remote chunks via u64 relaxed loads
    unsigned long long av[8][2];
    #pragma unroll
    for (int kc=0; kc<8; kc++){
      if (kc == ns){
        av[kc][0] = *(const unsigned long long*)&st[lm][lq*8];
        av[kc][1] = *(const unsigned long long*)&st[lm][lq*8 + 4];
      } else {
        unsigned long long* src = (unsigned long long*)(hcur + (size_t)lm*256 + kc*32 + lq*8);
        av[kc][0] = __hip_atomic_load(&src[0], __ATOMIC_RELAXED, __HIP_MEMORY_SCOPE_AGENT);
        av[kc][1] = __hip_atomic_load(&src[1], __ATOMIC_RELAXED, __HIP_MEMORY_SCOPE_AGENT);
      }
    }

    f32x4 acc[4];
    #pragma unroll
    for (int g=0; g<4; g++){ acc[g][0]=0.f; acc[g][1]=0.f; acc[g][2]=0.f; acc[g][3]=0.f; }

    #pragma unroll
    for (int kc=0; kc<8; kc++){
      union { unsigned long long u[2]; bf16x8 v; } au;
      au.u[0] = av[kc][0]; au.u[1] = av[kc][1];
      bf16x8 a = au.v;
      #pragma unroll
      for (int g=0; g<4; g++){
        bf16x8 b = *(const bf16x8*)&Ul[kc][g][jt][lane][0];
        acc[g] = __builtin_amdgcn_mfma_f32_16x16x32_bf16(a, b, acc[g], 0,0,0);
      }
    }

    __syncthreads();   // all st reads complete before overwrite

    #pragma unroll
    for (int r=0; r<4; r++){
      const int doc = lq*4 + r;
      float i_ = acc[0][r] + gx[0][r];
      float f_ = acc[1][r] + gx[1][r];
      float g_ = acc[2][r] + gx[2][r];
      float o_ = acc[3][r] + gx[3][r];
      float cn = sigf(f_)*cst[r] + sigf(i_)*tanhf_fast(g_);
      float hn = sigf(o_)*tanhf_fast(cn);
      cst[r] = cn;
      ushort_t hb = f2bf(hn);
      st[doc][jl] = hb;
      float ho = hn;
      if (mask_out && t >= dl_v[r]) ho = 0.f;
      outseq[((size_t)doc*SS + t)*DD + dir*HH + j] = ho;
    }

    __syncthreads();   // st complete

    // packed publish: 128 coalesced u64 stores (1 per thread)
    {
      const int doc = tid >> 3, j8 = tid & 7;
      unsigned long long v = *(const unsigned long long*)&st[doc][j8*4];
      __hip_atomic_store((unsigned long long*)(hnxt + (size_t)doc*256 + ns*32 + j8*4), v,
                         __ATOMIC_RELAXED, __HIP_MEMORY_SCOPE_AGENT);
    }
    __threadfence();
    __syncthreads();
    if (tid == 0)
      __hip_atomic_store(&flg[(size_t)step*8 + ns], 1u, __ATOMIC_RELEASE, __HIP_MEMORY_SCOPE_AGENT);
    p ^= 1;
  }
}

// ============ restricted attention (bf16 output for next GEMM) ============
__global__ __launch_bounds__(256) void k_attn(
    const float* __restrict__ X, const float* __restrict__ aw_,
    const float* __restrict__ ab_, const int* __restrict__ dl, ushort_t* __restrict__ hr)
{
  const int bs = blockIdx.x, b = bs / SS, s = bs % SS, tid = threadIdx.x;
  const float* xc = X + (size_t)bs*DD;
  ushort_t* outp = hr + (size_t)bs*(2*DD);
  for (int d=tid; d<DD; d+=256) outp[d] = f2bf(xc[d]);
  const int dlb = dl[b];
  if (s >= dlb){
    for (int d=tid; d<DD; d+=256) outp[DD+d] = 0;
    return;
  }
  __shared__ float xw[7][DD];
  __shared__ float red4[4][23];
  __shared__ float redm[23];
  for (int k=0;k<7;k++){
    int idx = s-3+k; idx = idx < 0 ? 0 : (idx > SS-1 ? SS-1 : idx);
    const float* row = X + ((size_t)b*SS + idx)*DD;
    for (int d=tid; d<DD; d+=256) xw[k][d] = row[d];
  }
  __syncthreads();
  float pv[23];
  #pragma unroll
  for (int i=0;i<23;i++) pv[i] = 0.f;
  #pragma unroll
  for (int pass=0; pass<2; pass++){
    int d = tid + pass*256;
    float xv = xc[d];
    pv[0] += xv*xv;
    pv[1] += xv * aw_[DD + d];
    float w1 = aw_[d];
    #pragma unroll
    for (int k=0;k<7;k++){
      float wv = xw[k][d];
      pv[2+3*k] += wv*xv;
      pv[3+3*k] += wv*wv;
      pv[4+3*k] += wv*w1;
    }
  }
  const int lane = tid & 63, wid = tid >> 6;
  #pragma unroll
  for (int i=0;i<23;i++){
    float v = pv[i];
    for (int o=32;o>0;o>>=1) v += __shfl_down(v, o, 64);
    if (lane==0) red4[wid][i] = v;
  }
  __syncthreads();
  if (tid < 23) redm[tid] = red4[0][tid]+red4[1][tid]+red4[2][tid]+red4[3][tid];
  __syncthreads();
  float nc = fmaxf(sqrtf(redm[0]), 1e-12f);
  float cterm = redm[1] + ab_[0];
  float wsim = aw_[2*DD];
  float sck[7]; float mx = -1e30f;
  #pragma unroll
  for (int k=0;k<7;k++){
    int idx = s-3+k;
    bool valid = (idx >= 0) && (idx < dlb);
    float nw = fmaxf(sqrtf(redm[3+3*k]), 1e-12f);
    float sim = sigf(redm[2+3*k] / (nw*nc));
    float sc = redm[4+3*k] + cterm + sim*wsim;
    sck[k] = valid ? sc : -1e30f;
    mx = fmaxf(mx, sck[k]);
  }
  float sum = 0.f;
  #pragma unroll
  for (int k=0;k<7;k++){ sck[k] = __expf(sck[k]-mx); sum += sck[k]; }
  float inv = 1.0f/sum;
  for (int d=tid; d<DD; d+=256){
    float cv = 0.f;
    #pragma unroll
    for (int k=0;k<7;k++) cv += sck[k]*xw[k][d];
    outp[DD+d] = f2bf(cv*inv);
  }
}

// ============ classifier + softmax ============
__global__ __launch_bounds__(256) void k_cls(
    const float* __restrict__ h2, const float* __restrict__ Wc,
    const float* __restrict__ bc, float* __restrict__ out)
{
  int pos = blockIdx.x*4 + (threadIdx.x >> 6);
  int lane = threadIdx.x & 63;
  const float* hv = h2 + (size_t)pos*DD;
  float a0 = 0.f, a1 = 0.f;
  for (int d=lane; d<DD; d+=64){ float h = hv[d]; a0 += h*Wc[d]; a1 += h*Wc[DD+d]; }
  for (int o=32;o>0;o>>=1){ a0 += __shfl_down(a0,o,64); a1 += __shfl_down(a1,o,64); }
  if (lane==0){
    float l0 = a0 + bc[0], l1 = a1 + bc[1];
    float m = fmaxf(l0,l1);
    float e0 = __expf(l0-m), e1 = __expf(l1-m);
    float s = e0+e1;
    out[pos*2]   = e0/s;
    out[pos*2+1] = e1/s;
  }
}

extern "C" void kernel_launch(void* const* d_in, const int* in_sizes, int n_in,
                              void* d_out, int out_size, void* d_ws, size_t ws_size,
                              hipStream_t stream) {
  const float* x    = (const float*)d_in[0];
  const int* slen   = (const int*)d_in[1];
  const int* dl     = (const int*)d_in[2];
  const float* wl_Wf=(const float*)d_in[3];
  const float* wl_Uf=(const float*)d_in[4];
  const float* wl_bf=(const float*)d_in[5];
  const float* wl_Wb=(const float*)d_in[6];
  const float* wl_Ub=(const float*)d_in[7];
  const float* wl_bb=(const float*)d_in[8];
  const float* sl_Wf=(const float*)d_in[9];
  const float* sl_Uf=(const float*)d_in[10];
  const float* sl_bf=(const float*)d_in[11];
  const float* sl_Wb=(const float*)d_in[12];
  const float* sl_Ub=(const float*)d_in[13];
  const float* sl_bb=(const float*)d_in[14];
  const float* attw =(const float*)d_in[15];
  const float* attb =(const float*)d_in[16];
  const float* m2_Wf=(const float*)d_in[17];
  const float* m2_Uf=(const float*)d_in[18];
  const float* m2_bf=(const float*)d_in[19];
  const float* m2_Wb=(const float*)d_in[20];
  const float* m2_Ub=(const float*)d_in[21];
  const float* m2_bb=(const float*)d_in[22];
  const float* clsW =(const float*)d_in[23];
  const float* clsb =(const float*)d_in[24];
  float* out = (float*)d_out;

  // ---- workspace layout (bytes) ----
  char* base = (char*)d_ws;
  ushort_t* xT  = (ushort_t*)base;                 // 47,185,920 (word phase)
  float* Gx1    = (float*)base;                    // reused after word phase
  float* Gx2    = (float*)(base + 12582912);
  ushort_t* hrb = (ushort_t*)(base + 25165824);
  float* hs     = (float*)(base + 28311552);
  float* h2     = (float*)(base + 31457280);
  char* pB = base + 47185920;
  ushort_t* WU     = (ushort_t*)pB;  pB += 2359296;   // [2][18][64][64][8]
  ushort_t* slWt   = (ushort_t*)pB;  pB += 2097152;
  ushort_t* slUt   = (ushort_t*)pB;  pB += 1048576;
  ushort_t* m2Wt   = (ushort_t*)pB;  pB += 4194304;
  ushort_t* m2Ut   = (ushort_t*)pB;  pB += 1048576;
  float*    maxacc = (float*)pB;     pB += 3145728;   // [1536][512]
  ushort_t* pooledb= (ushort_t*)pB;  pB += 1572864;   // [1536][512] bf16
  ushort_t* hbuf1  = (ushort_t*)pB;  pB += 32768;
  ushort_t* hbuf2  = (ushort_t*)pB;  pB += 32768;
  unsigned* flags1 = (unsigned*)pB;  pB += 6144;      // [2][96][8]
  unsigned* flags2 = (unsigned*)pB;  pB += 6144;
  const int ZERO_N = (32768+32768+6144+6144)/4;
  // phased-hoist state (7.86 MB) + Gxw slices (2 x L x 6.29 MB f32)
  float*    cstS = (float*)pB;  pB += 3145728;        // [96][512][16]
  float*    mvvS = (float*)pB;  pB += 3145728;        // [96][512][16]
  ushort_t* hstS = (ushort_t*)pB; pB += 1572864;      // [96][32][256]
  const size_t PERT = 6291456ull;                     // bytes per t per dir (f32 gates)
  size_t off = (size_t)(pB - base);
  int Lsel = 0;
  const int cand[5] = {48, 24, 12, 8, 4};
  for (int ci = 0; ci < 5; ci++){
    size_t need = 2ull * (size_t)cand[ci] * PERT;
    if (off + need <= ws_size){ Lsel = cand[ci]; break; }
  }
  float* gxwA = (float*)(base + off);
  float* gxwB = (float*)(base + off + (size_t)Lsel*PERT);

  // ---- conversions + sync arena zero ----
  k_zero   <<<(ZERO_N+127)/128, 128, 0, stream>>>((unsigned*)hbuf1, ZERO_N);
  k_cvt_x  <<<11520, 256, 0, stream>>>(x, xT);
  k_cvt_wu <<<576,   256, 0, stream>>>(wl_Wf, wl_Uf, wl_Wb, wl_Ub, WU);
  k_cvt_gen<<<512,   256, 0, stream>>>(sl_Wf, sl_Wb, slWt, DD);
  k_cvt_gen<<<256,   256, 0, stream>>>(sl_Uf, sl_Ub, slUt, HH);
  k_cvt_gen<<<1024,  256, 0, stream>>>(m2_Wf, m2_Wb, m2Wt, GG);
  k_cvt_gen<<<256,   256, 0, stream>>>(m2_Uf, m2_Ub, m2Ut, HH);

  // ---- word-level: time-sliced gates_x hoist + U-only recurrence (or fallback) ----
  if (Lsel > 0){
    const int NPH = WW / Lsel;
    for (int ph = 0; ph < NPH; ph++){
      k_gxw<<<dim3(96, Lsel/4, 4), 512, 0, stream>>>(xT, WU, wl_bf, wl_bb, gxwA, gxwB, Lsel, ph);
      k_word_u_phase<<<96, 512, 0, stream>>>(gxwA, gxwB, WU, maxacc, slen,
                                             cstS, mvvS, hstS, Lsel, ph, NPH);
    }
  } else {
    k_word_persist_full<<<96, 512, 0, stream>>>(xT, WU, wl_bf, wl_bb, maxacc, slen);
  }
  k_pool_maskb<<<(NSEQ*DD)/256, 256, 0, stream>>>(maxacc, pooledb, dl);

  // ---- sentence LSTM 1 (XCD-local, 128 blocks / 16 working) ----
  k_gemm_bf<<<dim3(24,8,2), 256, 0, stream>>>(pooledb, slWt, sl_bf, sl_bb, Gx1, DD);
  k_sstep_par<<<128, 128, 0, stream>>>(Gx1, slUt, hs, hbuf1, flags1, dl, 1);

  // ---- restricted attention ----
  k_attn<<<NSEQ, 256, 0, stream>>>(hs, attw, attb, dl, hrb);

  // ---- sentence LSTM 2 (XCD-local) ----
  k_gemm_bf<<<dim3(24,8,2), 256, 0, stream>>>(hrb, m2Wt, m2_bf, m2_bb, Gx2, GG);
  k_sstep_par<<<128, 128, 0, stream>>>(Gx2, m2Ut, h2, hbuf2, flags2, dl, 0);

  // ---- classifier ----
  k_cls<<<NSEQ/4, 256, 0, stream>>>(h2, clsW, clsb, out);
}

// Round 9
// 2242.959 us; speedup vs baseline: 1.2541x; 1.2541x over previous
//
#include <hip/hip_runtime.h>
#include <math.h>

#define BB 16
#define SS 96
#define WW 48
#define EE 300
#define HH 256
#define GG 1024   // 4H
#define DD 512    // 2H
#define NSEQ 1536 // B*S
#define NKCW 18   // word chunks: 10 x-chunks (K=320 padded) + 8 h-chunks (K=256)

typedef __attribute__((ext_vector_type(8))) short bf16x8;
typedef __attribute__((ext_vector_type(4))) float f32x4;
typedef unsigned short ushort_t;

__device__ __forceinline__ float sigf(float v){ return 1.0f/(1.0f+__expf(-v)); }
__device__ __forceinline__ float tanhf_fast(float v){ return 1.0f - 2.0f/(__expf(2.0f*v)+1.0f); }

__device__ __forceinline__ unsigned short f2bf(float f){
  union { float f; unsigned u; } v; v.f = f;
  unsigned u = v.u;
  u += 0x7FFFu + ((u>>16)&1u);   // RNE
  return (unsigned short)(u>>16);
}

// ============ conversions into MFMA-lane-linear layouts ============
// xT[grp 96][t 48][kc 10][lane 64][8]
__global__ __launch_bounds__(256) void k_cvt_x(const float* __restrict__ x, ushort_t* __restrict__ xT){
  int i = blockIdx.x*256 + threadIdx.x;        // 96*48*10*64 groups
  int l = i & 63;
  int q = i >> 6;
  int kc = q % 10; q /= 10;
  int t  = q % 48;
  int grp = q / 48;
  int row = grp*16 + (l & 15);
  int e = kc*32 + (l >> 4)*8;
  const float* src = x + ((size_t)row*WW + t)*EE + e;
  ushort_t* dst = xT + (size_t)i*8;
  #pragma unroll
  for (int d=0; d<8; d++) dst[d] = (e+d < EE) ? f2bf(src[d]) : 0;
}

// WU[dir][kc 18][nt 64][lane 64][8]: kc<10 from W (K=320 pad of 300), kc>=10 from U (K=256)
__global__ __launch_bounds__(256) void k_cvt_wu(
    const float* __restrict__ Wf, const float* __restrict__ Uf,
    const float* __restrict__ Wb_, const float* __restrict__ Ub_,
    ushort_t* __restrict__ WU){
  int i = blockIdx.x*256 + threadIdx.x;        // 2*18*64*64 groups
  int l = i & 63;
  int nt = (i >> 6) & 63;
  int kc = (i >> 12) % NKCW;
  int dir = i / (NKCW*4096);
  int n = nt*16 + (l & 15);
  int lq8 = (l >> 4)*8;
  ushort_t* dst = WU + (size_t)i*8;
  if (kc < 10){
    int e = kc*32 + lq8;
    const float* src = (dir ? Wb_ : Wf) + (size_t)n*EE + e;
    #pragma unroll
    for (int d=0; d<8; d++) dst[d] = (e+d < EE) ? f2bf(src[d]) : 0;
  } else {
    int e = (kc-10)*32 + lq8;
    const float* src = (dir ? Ub_ : Uf) + (size_t)n*HH + e;
    #pragma unroll
    for (int d=0; d<8; d++) dst[d] = f2bf(src[d]);
  }
}

// Bt[dir][kc K/32][nt 64][lane 64][8] from row-major [1024][K] (per dir)
__global__ __launch_bounds__(256) void k_cvt_gen(
    const float* __restrict__ A0, const float* __restrict__ A1,
    ushort_t* __restrict__ Bt, int K){
  int i = blockIdx.x*256 + threadIdx.x;        // 2*(K/32)*64*64 groups
  int l = i & 63;
  int nt = (i >> 6) & 63;
  int nk = K >> 5;
  int kc = (i >> 12) % nk;
  int dir = i / (nk*4096);
  int n = nt*16 + (l & 15);
  int e = kc*32 + (l >> 4)*8;
  const float* src = (dir ? A1 : A0) + (size_t)n*K + e;
  ushort_t* dst = Bt + (size_t)i*8;
  #pragma unroll
  for (int d=0; d<8; d++) dst[d] = f2bf(src[d]);
}

// zero the sync/exchange arena
__global__ __launch_bounds__(128) void k_zero(unsigned* __restrict__ p, int n){
  int i = blockIdx.x*128 + threadIdx.x;
  if (i < n) p[i] = 0u;
}

// ============ pre-GEMM: gates_x for the word level, TIME-SLICED ============
__global__ __launch_bounds__(512) void k_gxw(
    const ushort_t* __restrict__ xT,   // [96][48][10][64][8]
    const ushort_t* __restrict__ WU,   // [2][18][64][64][8] (kc<10 = W-part)
    const float* __restrict__ bf_, const float* __restrict__ bb_,
    float* __restrict__ gxwA, float* __restrict__ gxwB,
    int L, int ph)
{
  const int grp = blockIdx.x;
  const int t0l = blockIdx.y*4;        // local t within slice
  const int dir = blockIdx.z >> 1;
  const int jh  = blockIdx.z & 1;
  const int tid = threadIdx.x;
  const int ng = tid >> 6, lane = tid & 63;
  const int lm = lane & 15, lq = lane >> 4;
  const int jt = jh*8 + ng;            // 0..15
  const int jc = jt*16 + lm;           // 0..255

  const int tbase = dir ? (WW - (ph+1)*L) : (ph*L);   // global t = tbase + t0l + tt
  float* GxS = dir ? gxwB : gxwA;

  const ushort_t* WUD = WU + (size_t)dir*NKCW*4096*8;
  const float* bias = dir ? bb_ : bf_;
  float bias_v[4];
  #pragma unroll
  for (int g=0; g<4; g++) bias_v[g] = bias[g*256 + jc];

  const ushort_t* xg = xT + ((size_t)grp*48 + (tbase + t0l))*10*512;

  bf16x8 curB[4], nxtB[4], curA[4], nxtA[4];
  #pragma unroll
  for (int g=0; g<4; g++)
    curB[g] = *(const bf16x8*)(WUD + ((size_t)(g*16 + jt)*64 + lane)*8);
  #pragma unroll
  for (int tt=0; tt<4; tt++)
    curA[tt] = *(const bf16x8*)(xg + (size_t)tt*10*512 + lane*8);

  f32x4 acc[4][4];
  #pragma unroll
  for (int tt=0; tt<4; tt++)
    #pragma unroll
    for (int g=0; g<4; g++){ acc[tt][g][0]=0.f; acc[tt][g][1]=0.f; acc[tt][g][2]=0.f; acc[tt][g][3]=0.f; }

  #pragma unroll
  for (int kc=0; kc<10; kc++){
    if (kc < 9){
      const int k1 = kc+1;
      #pragma unroll
      for (int g=0; g<4; g++)
        nxtB[g] = *(const bf16x8*)(WUD + ((size_t)k1*4096 + (g*16 + jt)*64 + lane)*8);
      #pragma unroll
      for (int tt=0; tt<4; tt++)
        nxtA[tt] = *(const bf16x8*)(xg + (size_t)tt*10*512 + k1*512 + lane*8);
    }
    #pragma unroll
    for (int tt=0; tt<4; tt++)
      #pragma unroll
      for (int g=0; g<4; g++)
        acc[tt][g] = __builtin_amdgcn_mfma_f32_16x16x32_bf16(curA[tt], curB[g], acc[tt][g], 0,0,0);
    #pragma unroll
    for (int g=0; g<4; g++) curB[g] = nxtB[g];
    #pragma unroll
    for (int tt=0; tt<4; tt++) curA[tt] = nxtA[tt];
  }

  f32x4* GxV = (f32x4*)GxS;
  #pragma unroll
  for (int tt=0; tt<4; tt++)
    #pragma unroll
    for (int r=0; r<4; r++){
      f32x4 v;
      v[0] = acc[tt][0][r] + bias_v[0];
      v[1] = acc[tt][1][r] + bias_v[1];
      v[2] = acc[tt][2][r] + bias_v[2];
      v[3] = acc[tt][3][r] + bias_v[3];
      GxV[(((size_t)grp*L + (t0l+tt))*16 + lq*4 + r)*256 + jc] = v;
    }
}

// ============ word-level recurrent BiLSTM, U-only, PHASED ============
// Gxw reads hoisted to the TOP of each step (h-independent) so their HBM
// latency hides under the MFMA chain (R7 edit, kept).
__global__ __launch_bounds__(512) void k_word_u_phase(
    const float* __restrict__ gxwA, const float* __restrict__ gxwB,
    const ushort_t* __restrict__ WU,   // U chunks at [dir][10..17][..]
    float* __restrict__ maxacc,        // [1536][512]
    const int* __restrict__ slen,
    float* __restrict__ cstS,          // [96][512][16]
    float* __restrict__ mvvS,          // [96][512][16]
    ushort_t* __restrict__ hstS,       // [96][32][256]
    int L, int ph, int NPH)
{
  const int id = blockIdx.x;
  const int xcd = id & 7;
  const int dir = xcd & 1;
  const int bx = (xcd >> 1)*12 + (id >> 3);
  const int tid = threadIdx.x;
  const int ng = tid >> 6, lane = tid & 63;
  const int lm = lane & 15, lq = lane >> 4;
  const int jt0 = ng*32;

  __shared__ __align__(16) ushort_t hlds[2][32][264];
  for (int i = tid; i < 2*32*264/2; i += 512) ((unsigned*)hlds)[i] = 0u;
  __syncthreads();

  const ushort_t* UD = WU + (size_t)dir*NKCW*4096*8 + (size_t)10*4096*8;
  int ntb[4][2];
  #pragma unroll
  for (int g=0; g<4; g++)
    #pragma unroll
    for (int jt=0; jt<2; jt++) ntb[g][jt] = g*16 + ng*2 + jt;

  int slen_v[2][4];
  #pragma unroll
  for (int mh=0; mh<2; mh++)
    #pragma unroll
    for (int r=0; r<4; r++) slen_v[mh][r] = slen[bx*32 + mh*16 + lq*4 + r];

  float cst[2][2][4], mvv[2][2][4];
  if (ph == 0){
    #pragma unroll
    for (int mh=0; mh<2; mh++)
      #pragma unroll
      for (int jt=0; jt<2; jt++)
        #pragma unroll
        for (int r=0; r<4; r++){ cst[mh][jt][r]=0.f; mvv[mh][jt][r]=-1e30f; }
  } else {
    const float* cb = cstS + ((size_t)id*512 + tid)*16;
    const float* mb = mvvS + ((size_t)id*512 + tid)*16;
    #pragma unroll
    for (int mh=0; mh<2; mh++)
      #pragma unroll
      for (int jt=0; jt<2; jt++)
        #pragma unroll
        for (int r=0; r<4; r++){ cst[mh][jt][r]=cb[mh*8+jt*4+r]; mvv[mh][jt][r]=mb[mh*8+jt*4+r]; }
    const unsigned long long* hs = (const unsigned long long*)(hstS + (size_t)id*32*256);
    for (int i = tid; i < 2048; i += 512){
      int row = i >> 6, c8 = i & 63;
      *(unsigned long long*)&hlds[0][row][c8*4] = hs[i];
    }
  }

  const f32x4* GxS = (const f32x4*)(dir ? gxwB : gxwA);

  __syncthreads();
  int p = 0;

  for (int step=0; step<L; step++){
    const int t  = dir ? (WW-1 - ph*L - step) : (ph*L + step);   // global timestep
    const int tl = dir ? (L-1-step) : step;                      // local slice index

    // gates_x loads issued FIRST (h-independent) — hide under the MFMA chain
    f32x4 gxv[2][2][4];
    #pragma unroll
    for (int mh=0; mh<2; mh++)
      #pragma unroll
      for (int jt=0; jt<2; jt++)
        #pragma unroll
        for (int r=0; r<4; r++)
          gxv[mh][jt][r] = GxS[(((size_t)(bx*2+mh)*L + tl)*16 + lq*4 + r)*256 + jt0 + jt*16 + lm];

    bf16x8 curB[4][2], nxtB[4][2];
    bf16x8 curA0, curA1, nxtA0, nxtA1;
    #pragma unroll
    for (int g=0; g<4; g++)
      #pragma unroll
      for (int jt=0; jt<2; jt++)
        curB[g][jt] = *(const bf16x8*)(UD + ((size_t)ntb[g][jt]*64 + lane)*8);
    curA0 = *(const bf16x8*)&hlds[p][lm][lq*8];
    curA1 = *(const bf16x8*)&hlds[p][16+lm][lq*8];

    f32x4 acc[2][4][2];
    #pragma unroll
    for (int mh=0; mh<2; mh++)
      #pragma unroll
      for (int g=0; g<4; g++)
        #pragma unroll
        for (int jt=0; jt<2; jt++){ acc[mh][g][jt][0]=0.f; acc[mh][g][jt][1]=0.f; acc[mh][g][jt][2]=0.f; acc[mh][g][jt][3]=0.f; }

    #pragma unroll
    for (int kc=0; kc<8; kc++){
      if (kc < 7){
        const int k1 = kc+1;
        #pragma unroll
        for (int g=0; g<4; g++)
          #pragma unroll
          for (int jt=0; jt<2; jt++)
            nxtB[g][jt] = *(const bf16x8*)(UD + ((size_t)k1*4096 + ntb[g][jt]*64 + lane)*8);
        const int ko = k1*32 + lq*8;
        nxtA0 = *(const bf16x8*)&hlds[p][lm][ko];
        nxtA1 = *(const bf16x8*)&hlds[p][16+lm][ko];
      }
      #pragma unroll
      for (int g=0; g<4; g++)
        #pragma unroll
        for (int jt=0; jt<2; jt++){
          acc[0][g][jt] = __builtin_amdgcn_mfma_f32_16x16x32_bf16(curA0, curB[g][jt], acc[0][g][jt], 0,0,0);
          acc[1][g][jt] = __builtin_amdgcn_mfma_f32_16x16x32_bf16(curA1, curB[g][jt], acc[1][g][jt], 0,0,0);
        }
      #pragma unroll
      for (int g=0; g<4; g++)
        #pragma unroll
        for (int jt=0; jt<2; jt++) curB[g][jt] = nxtB[g][jt];
      curA0 = nxtA0; curA1 = nxtA1;
    }

    #pragma unroll
    for (int mh=0; mh<2; mh++)
      #pragma unroll
      for (int jt=0; jt<2; jt++)
        #pragma unroll
        for (int r=0; r<4; r++){
          float i_ = acc[mh][0][jt][r] + gxv[mh][jt][r][0];
          float f_ = acc[mh][1][jt][r] + gxv[mh][jt][r][1];
          float g_ = acc[mh][2][jt][r] + gxv[mh][jt][r][2];
          float o_ = acc[mh][3][jt][r] + gxv[mh][jt][r][3];
          float cn = sigf(f_)*cst[mh][jt][r] + sigf(i_)*tanhf_fast(g_);
          float hn = sigf(o_)*tanhf_fast(cn);
          cst[mh][jt][r] = cn;
          if (t < slen_v[mh][r]) mvv[mh][jt][r] = fmaxf(mvv[mh][jt][r], hn);
          hlds[1-p][mh*16 + lq*4 + r][jt0 + jt*16 + lm] = f2bf(hn);
        }
    __syncthreads();
    p ^= 1;
  }

  if (ph < NPH-1){
    float* cb = cstS + ((size_t)id*512 + tid)*16;
    float* mb = mvvS + ((size_t)id*512 + tid)*16;
    #pragma unroll
    for (int mh=0; mh<2; mh++)
      #pragma unroll
      for (int jt=0; jt<2; jt++)
        #pragma unroll
        for (int r=0; r<4; r++){ cb[mh*8+jt*4+r]=cst[mh][jt][r]; mb[mh*8+jt*4+r]=mvv[mh][jt][r]; }
    unsigned long long* hsv = (unsigned long long*)(hstS + (size_t)id*32*256);
    for (int i = tid; i < 2048; i += 512){
      int row = i >> 6, c8 = i & 63;
      hsv[i] = *(const unsigned long long*)&hlds[0][row][c8*4];
    }
  } else {
    #pragma unroll
    for (int mh=0; mh<2; mh++)
      #pragma unroll
      for (int jt=0; jt<2; jt++)
        #pragma unroll
        for (int r=0; r<4; r++)
          maxacc[(size_t)(bx*32 + mh*16 + lq*4 + r)*DD + dir*HH + jt0 + jt*16 + lm] = mvv[mh][jt][r];
  }
}

// ============ word-level persistent BiLSTM — FALLBACK (ws too small) ============
__global__ __launch_bounds__(512) __attribute__((amdgpu_waves_per_eu(2, 2))) void k_word_persist_full(
    const ushort_t* __restrict__ xT,
    const ushort_t* __restrict__ WU,
    const float* __restrict__ bf_, const float* __restrict__ bb_,
    float* __restrict__ maxacc,
    const int* __restrict__ slen)
{
  const int id = blockIdx.x;
  const int xcd = id & 7;
  const int dir = xcd & 1;
  const int bx = (xcd >> 1)*12 + (id >> 3);
  const int tid = threadIdx.x;
  const int ng = tid >> 6, lane = tid & 63;
  const int lm = lane & 15, lq = lane >> 4;
  const int jt0 = ng*32;

  __shared__ __align__(16) ushort_t hlds[2][32][264];
  for (int i = tid; i < 2*32*264/2; i += 512) ((unsigned*)hlds)[i] = 0u;

  const ushort_t* WUD = WU + (size_t)dir*NKCW*4096*8;
  int ntb[4][2];
  #pragma unroll
  for (int g=0; g<4; g++)
    #pragma unroll
    for (int jt=0; jt<2; jt++) ntb[g][jt] = g*16 + ng*2 + jt;

  const float* bias = dir ? bb_ : bf_;
  float bias_v[4][2];
  #pragma unroll
  for (int g=0; g<4; g++)
    #pragma unroll
    for (int jt=0; jt<2; jt++) bias_v[g][jt] = bias[g*256 + jt0 + jt*16 + lm];

  int slen_v[2][4];
  #pragma unroll
  for (int mh=0; mh<2; mh++)
    #pragma unroll
    for (int r=0; r<4; r++) slen_v[mh][r] = slen[bx*32 + mh*16 + lq*4 + r];

  float cst[2][2][4], mvv[2][2][4];
  #pragma unroll
  for (int mh=0; mh<2; mh++)
    #pragma unroll
    for (int jt=0; jt<2; jt++)
      #pragma unroll
      for (int r=0; r<4; r++){ cst[mh][jt][r]=0.f; mvv[mh][jt][r]=-1e30f; }

  const ushort_t* xg0 = xT + (size_t)(bx*2+0)*48*10*512;
  const ushort_t* xg1 = xT + (size_t)(bx*2+1)*48*10*512;

  __syncthreads();
  int p = 0;

  for (int step=0; step<WW; step++){
    const int t = dir ? (WW-1-step) : step;
    const size_t xoff = (size_t)t*10*512 + lane*8;

    bf16x8 curB[4][2], nxtB[4][2];
    bf16x8 curA0, curA1, nxtA0, nxtA1;
    #pragma unroll
    for (int g=0; g<4; g++)
      #pragma unroll
      for (int jt=0; jt<2; jt++)
        curB[g][jt] = *(const bf16x8*)(WUD + ((size_t)ntb[g][jt]*64 + lane)*8);
    curA0 = *(const bf16x8*)(xg0 + xoff);
    curA1 = *(const bf16x8*)(xg1 + xoff);

    f32x4 acc[2][4][2];
    #pragma unroll
    for (int mh=0; mh<2; mh++)
      #pragma unroll
      for (int g=0; g<4; g++)
        #pragma unroll
        for (int jt=0; jt<2; jt++){ acc[mh][g][jt][0]=0.f; acc[mh][g][jt][1]=0.f; acc[mh][g][jt][2]=0.f; acc[mh][g][jt][3]=0.f; }

    #pragma unroll
    for (int kc=0; kc<NKCW; kc++){
      if (kc < NKCW-1){
        const int k1 = kc+1;
        #pragma unroll
        for (int g=0; g<4; g++)
          #pragma unroll
          for (int jt=0; jt<2; jt++)
            nxtB[g][jt] = *(const bf16x8*)(WUD + ((size_t)k1*4096 + ntb[g][jt]*64 + lane)*8);
        if (k1 < 10){
          nxtA0 = *(const bf16x8*)(xg0 + xoff + k1*512);
          nxtA1 = *(const bf16x8*)(xg1 + xoff + k1*512);
        } else {
          const int ko = (k1-10)*32 + lq*8;
          nxtA0 = *(const bf16x8*)&hlds[p][lm][ko];
          nxtA1 = *(const bf16x8*)&hlds[p][16+lm][ko];
        }
      }
      #pragma unroll
      for (int g=0; g<4; g++)
        #pragma unroll
        for (int jt=0; jt<2; jt++){
          acc[0][g][jt] = __builtin_amdgcn_mfma_f32_16x16x32_bf16(curA0, curB[g][jt], acc[0][g][jt], 0,0,0);
          acc[1][g][jt] = __builtin_amdgcn_mfma_f32_16x16x32_bf16(curA1, curB[g][jt], acc[1][g][jt], 0,0,0);
        }
      #pragma unroll
      for (int g=0; g<4; g++)
        #pragma unroll
        for (int jt=0; jt<2; jt++) curB[g][jt] = nxtB[g][jt];
      curA0 = nxtA0; curA1 = nxtA1;
    }

    #pragma unroll
    for (int mh=0; mh<2; mh++)
      #pragma unroll
      for (int jt=0; jt<2; jt++)
        #pragma unroll
        for (int r=0; r<4; r++){
          float i_ = acc[mh][0][jt][r] + bias_v[0][jt];
          float f_ = acc[mh][1][jt][r] + bias_v[1][jt];
          float g_ = acc[mh][2][jt][r] + bias_v[2][jt];
          float o_ = acc[mh][3][jt][r] + bias_v[3][jt];
          float cn = sigf(f_)*cst[mh][jt][r] + sigf(i_)*tanhf_fast(g_);
          float hn = sigf(o_)*tanhf_fast(cn);
          cst[mh][jt][r] = cn;
          if (t < slen_v[mh][r]) mvv[mh][jt][r] = fmaxf(mvv[mh][jt][r], hn);
          hlds[1-p][mh*16 + lq*4 + r][jt0 + jt*16 + lm] = f2bf(hn);
        }
    __syncthreads();
    p ^= 1;
  }
  #pragma unroll
  for (int mh=0; mh<2; mh++)
    #pragma unroll
    for (int jt=0; jt<2; jt++)
      #pragma unroll
      for (int r=0; r<4; r++)
        maxacc[(size_t)(bx*32 + mh*16 + lq*4 + r)*DD + dir*HH + jt0 + jt*16 + lm] = mvv[mh][jt][r];
}

// ============ maxpool mask -> bf16 pooled ============
__global__ __launch_bounds__(256) void k_pool_maskb(
    const float* __restrict__ maxacc, ushort_t* __restrict__ pooled_bf, const int* __restrict__ dl)
{
  int i = blockIdx.x*256 + threadIdx.x;       // NSEQ*DD
  int m = i / DD; int b = m / SS; int s = m % SS;
  pooled_bf[i] = (s < dl[b]) ? f2bf(maxacc[i]) : 0;
}

// ============ bf16 GEMM: C[z][1536xGG] = A[1536xK] @ B[z] + bias (B lane-linear) ============
__global__ __launch_bounds__(256) void k_gemm_bf(
    const ushort_t* __restrict__ A,
    const ushort_t* __restrict__ Bt,      // [2][K/32][64][64][8]
    const float* __restrict__ bias0, const float* __restrict__ bias1,
    float* __restrict__ C,                // [2][NSEQ][GG]
    int K)
{
  const int z = blockIdx.z;
  const int nk = K >> 5;
  const ushort_t* BD = Bt + (size_t)z*nk*4096*8;
  const float* bias = z ? bias1 : bias0;
  float* Cz = C + (size_t)z*NSEQ*GG;

  const int tid = threadIdx.x;
  const int w = tid >> 6, lane = tid & 63;
  const int lm = lane & 15, lq = lane >> 4;
  const int m0 = blockIdx.x*64 + w*16, nt0 = blockIdx.y*8;

  const ushort_t* arow = A + (size_t)(m0+lm)*K + lq*8;

  f32x4 acc[8];
  #pragma unroll
  for (int j=0; j<8; j++){ acc[j][0]=0.f; acc[j][1]=0.f; acc[j][2]=0.f; acc[j][3]=0.f; }

  #pragma unroll 4
  for (int kc=0; kc<nk; kc++){
    bf16x8 a = *(const bf16x8*)(arow + kc*32);
    #pragma unroll
    for (int j=0; j<8; j++){
      bf16x8 b = *(const bf16x8*)(BD + ((size_t)kc*4096 + (nt0+j)*64 + lane)*8);
      acc[j] = __builtin_amdgcn_mfma_f32_16x16x32_bf16(a, b, acc[j], 0,0,0);
    }
  }
  #pragma unroll
  for (int j=0; j<8; j++){
    int n = (nt0+j)*16 + lm;
    float bv = bias[n];
    #pragma unroll
    for (int r=0; r<4; r++)
      Cz[(size_t)(m0 + lq*4 + r)*GG + n] = acc[j][r] + bv;
  }
}

// ============ sentence-level LSTM, PARALLEL across 16 blocks — v1 sync (reverted) ============
// R8 post-mortem: v2 (packed publish / per-producer flags) = 433 us, v3
// (+XCD-local placement + relaxed spin) = 670 us, v1 = 397 us. Agent-scope
// sync cost is ROUND-TRIP latency at the memory-side coherence point and is
// invariant to transaction shape AND block placement; co-location only adds
// L2 contention. v1 is the empirical floor for this structure — restored
// byte-for-byte from R6.
__global__ __launch_bounds__(128) void k_sstep_par(
    const float* __restrict__ Gx,     // [2][1536][1024], bias included
    const ushort_t* __restrict__ Ut,  // [2][8][64][64][8]
    float* __restrict__ outseq,       // [16][96][512]
    ushort_t* __restrict__ hbuf,      // [2 parity][2 dir][16 doc][256] bf16, pre-zeroed
    unsigned* __restrict__ flags,     // [2 dir][96], pre-zeroed
    const int* __restrict__ dl, int mask_out)
{
  const int dir = blockIdx.x >> 3;
  const int ns  = blockIdx.x & 7;
  const int tid = threadIdx.x;
  const int jt  = tid >> 6;
  const int lane = tid & 63, lm = lane & 15, lq = lane >> 4;

  __shared__ __align__(16) ushort_t Ul[8][4][2][64][8];   // 64 KB

  {
    const ushort_t* UD = Ut + (size_t)dir*8*4096*8;
    for (int v = tid; v < 4096; v += 128){
      int lane_v = v & 63;
      int q = v >> 6;
      int jv = q & 1, gq = (q >> 1) & 3, kcv = q >> 3;
      const uint4* src = (const uint4*)(UD + ((size_t)kcv*4096 + (gq*16 + ns*2 + jv)*64 + lane_v)*8);
      ((uint4*)Ul)[v] = *src;
    }
  }

  int dl_v[4];
  #pragma unroll
  for (int r=0; r<4; r++) dl_v[r] = dl[lq*4 + r];

  float cst[4];
  #pragma unroll
  for (int r=0; r<4; r++) cst[r] = 0.f;

  unsigned* flg = flags + dir*SS;
  const float* GxD = Gx + (size_t)dir*NSEQ*GG;
  ushort_t* hb0 = hbuf + (size_t)dir*16*256;
  ushort_t* hb1 = hbuf + (size_t)(2+dir)*16*256;
  const int j = ns*32 + jt*16 + lm;

  __syncthreads();
  int p = 0;

  for (int step=0; step<SS; step++){
    const int t = dir ? (SS-1-step) : step;

    if (step > 0){
      if (tid == 0){
        while (__hip_atomic_load(&flg[step-1], __ATOMIC_ACQUIRE, __HIP_MEMORY_SCOPE_AGENT) < 8u) {}
      }
      __syncthreads();
    }
    ushort_t* hcur = p ? hb1 : hb0;
    ushort_t* hnxt = p ? hb0 : hb1;

    unsigned long long av[8][2];
    #pragma unroll
    for (int kc=0; kc<8; kc++){
      unsigned long long* src = (unsigned long long*)(hcur + (size_t)lm*256 + kc*32 + lq*8);
      av[kc][0] = __hip_atomic_load(&src[0], __ATOMIC_RELAXED, __HIP_MEMORY_SCOPE_AGENT);
      av[kc][1] = __hip_atomic_load(&src[1], __ATOMIC_RELAXED, __HIP_MEMORY_SCOPE_AGENT);
    }

    float gx[4][4];
    #pragma unroll
    for (int g=0; g<4; g++)
      #pragma unroll
      for (int r=0; r<4; r++)
        gx[g][r] = GxD[((size_t)(lq*4+r)*SS + t)*GG + g*256 + j];

    f32x4 acc[4];
    #pragma unroll
    for (int g=0; g<4; g++){ acc[g][0]=0.f; acc[g][1]=0.f; acc[g][2]=0.f; acc[g][3]=0.f; }

    #pragma unroll
    for (int kc=0; kc<8; kc++){
      union { unsigned long long u[2]; bf16x8 v; } au;
      au.u[0] = av[kc][0]; au.u[1] = av[kc][1];
      bf16x8 a = au.v;
      #pragma unroll
      for (int g=0; g<4; g++){
        bf16x8 b = *(const bf16x8*)&Ul[kc][g][jt][lane][0];
        acc[g] = __builtin_amdgcn_mfma_f32_16x16x32_bf16(a, b, acc[g], 0,0,0);
      }
    }

    #pragma unroll
    for (int r=0; r<4; r++){
      const int doc = lq*4 + r;
      float i_ = acc[0][r] + gx[0][r];
      float f_ = acc[1][r] + gx[1][r];
      float g_ = acc[2][r] + gx[2][r];
      float o_ = acc[3][r] + gx[3][r];
      float cn = sigf(f_)*cst[r] + sigf(i_)*tanhf_fast(g_);
      float hn = sigf(o_)*tanhf_fast(cn);
      cst[r] = cn;
      __hip_atomic_store(&hnxt[(size_t)doc*256 + j], (ushort_t)f2bf(hn),
                         __ATOMIC_RELAXED, __HIP_MEMORY_SCOPE_AGENT);
      float ho = hn;
      if (mask_out && t >= dl_v[r]) ho = 0.f;
      outseq[((size_t)doc*SS + t)*DD + dir*HH + j] = ho;
    }

    __threadfence();
    __syncthreads();
    if (tid == 0)
      __hip_atomic_fetch_add(&flg[step], 1u, __ATOMIC_RELEASE, __HIP_MEMORY_SCOPE_AGENT);
    p ^= 1;
  }
}

// ============ restricted attention (bf16 output for next GEMM) ============
__global__ __launch_bounds__(256) void k_attn(
    const float* __restrict__ X, const float* __restrict__ aw_,
    const float* __restrict__ ab_, const int* __restrict__ dl, ushort_t* __restrict__ hr)
{
  const int bs = blockIdx.x, b = bs / SS, s = bs % SS, tid = threadIdx.x;
  const float* xc = X + (size_t)bs*DD;
  ushort_t* outp = hr + (size_t)bs*(2*DD);
  for (int d=tid; d<DD; d+=256) outp[d] = f2bf(xc[d]);
  const int dlb = dl[b];
  if (s >= dlb){
    for (int d=tid; d<DD; d+=256) outp[DD+d] = 0;
    return;
  }
  __shared__ float xw[7][DD];
  __shared__ float red4[4][23];
  __shared__ float redm[23];
  for (int k=0;k<7;k++){
    int idx = s-3+k; idx = idx < 0 ? 0 : (idx > SS-1 ? SS-1 : idx);
    const float* row = X + ((size_t)b*SS + idx)*DD;
    for (int d=tid; d<DD; d+=256) xw[k][d] = row[d];
  }
  __syncthreads();
  float pv[23];
  #pragma unroll
  for (int i=0;i<23;i++) pv[i] = 0.f;
  #pragma unroll
  for (int pass=0; pass<2; pass++){
    int d = tid + pass*256;
    float xv = xc[d];
    pv[0] += xv*xv;
    pv[1] += xv * aw_[DD + d];
    float w1 = aw_[d];
    #pragma unroll
    for (int k=0;k<7;k++){
      float wv = xw[k][d];
      pv[2+3*k] += wv*xv;
      pv[3+3*k] += wv*wv;
      pv[4+3*k] += wv*w1;
    }
  }
  const int lane = tid & 63, wid = tid >> 6;
  #pragma unroll
  for (int i=0;i<23;i++){
    float v = pv[i];
    for (int o=32;o>0;o>>=1) v += __shfl_down(v, o, 64);
    if (lane==0) red4[wid][i] = v;
  }
  __syncthreads();
  if (tid < 23) redm[tid] = red4[0][tid]+red4[1][tid]+red4[2][tid]+red4[3][tid];
  __syncthreads();
  float nc = fmaxf(sqrtf(redm[0]), 1e-12f);
  float cterm = redm[1] + ab_[0];
  float wsim = aw_[2*DD];
  float sck[7]; float mx = -1e30f;
  #pragma unroll
  for (int k=0;k<7;k++){
    int idx = s-3+k;
    bool valid = (idx >= 0) && (idx < dlb);
    float nw = fmaxf(sqrtf(redm[3+3*k]), 1e-12f);
    float sim = sigf(redm[2+3*k] / (nw*nc));
    float sc = redm[4+3*k] + cterm + sim*wsim;
    sck[k] = valid ? sc : -1e30f;
    mx = fmaxf(mx, sck[k]);
  }
  float sum = 0.f;
  #pragma unroll
  for (int k=0;k<7;k++){ sck[k] = __expf(sck[k]-mx); sum += sck[k]; }
  float inv = 1.0f/sum;
  for (int d=tid; d<DD; d+=256){
    float cv = 0.f;
    #pragma unroll
    for (int k=0;k<7;k++) cv += sck[k]*xw[k][d];
    outp[DD+d] = f2bf(cv*inv);
  }
}

// ============ classifier + softmax ============
__global__ __launch_bounds__(256) void k_cls(
    const float* __restrict__ h2, const float* __restrict__ Wc,
    const float* __restrict__ bc, float* __restrict__ out)
{
  int pos = blockIdx.x*4 + (threadIdx.x >> 6);
  int lane = threadIdx.x & 63;
  const float* hv = h2 + (size_t)pos*DD;
  float a0 = 0.f, a1 = 0.f;
  for (int d=lane; d<DD; d+=64){ float h = hv[d]; a0 += h*Wc[d]; a1 += h*Wc[DD+d]; }
  for (int o=32;o>0;o>>=1){ a0 += __shfl_down(a0,o,64); a1 += __shfl_down(a1,o,64); }
  if (lane==0){
    float l0 = a0 + bc[0], l1 = a1 + bc[1];
    float m = fmaxf(l0,l1);
    float e0 = __expf(l0-m), e1 = __expf(l1-m);
    float s = e0+e1;
    out[pos*2]   = e0/s;
    out[pos*2+1] = e1/s;
  }
}

extern "C" void kernel_launch(void* const* d_in, const int* in_sizes, int n_in,
                              void* d_out, int out_size, void* d_ws, size_t ws_size,
                              hipStream_t stream) {
  const float* x    = (const float*)d_in[0];
  const int* slen   = (const int*)d_in[1];
  const int* dl     = (const int*)d_in[2];
  const float* wl_Wf=(const float*)d_in[3];
  const float* wl_Uf=(const float*)d_in[4];
  const float* wl_bf=(const float*)d_in[5];
  const float* wl_Wb=(const float*)d_in[6];
  const float* wl_Ub=(const float*)d_in[7];
  const float* wl_bb=(const float*)d_in[8];
  const float* sl_Wf=(const float*)d_in[9];
  const float* sl_Uf=(const float*)d_in[10];
  const float* sl_bf=(const float*)d_in[11];
  const float* sl_Wb=(const float*)d_in[12];
  const float* sl_Ub=(const float*)d_in[13];
  const float* sl_bb=(const float*)d_in[14];
  const float* attw =(const float*)d_in[15];
  const float* attb =(const float*)d_in[16];
  const float* m2_Wf=(const float*)d_in[17];
  const float* m2_Uf=(const float*)d_in[18];
  const float* m2_bf=(const float*)d_in[19];
  const float* m2_Wb=(const float*)d_in[20];
  const float* m2_Ub=(const float*)d_in[21];
  const float* m2_bb=(const float*)d_in[22];
  const float* clsW =(const float*)d_in[23];
  const float* clsb =(const float*)d_in[24];
  float* out = (float*)d_out;

  // ---- workspace layout (bytes) ----
  char* base = (char*)d_ws;
  ushort_t* xT  = (ushort_t*)base;                 // 47,185,920 (word phase)
  float* Gx1    = (float*)base;                    // reused after word phase
  float* Gx2    = (float*)(base + 12582912);
  ushort_t* hrb = (ushort_t*)(base + 25165824);
  float* hs     = (float*)(base + 28311552);
  float* h2     = (float*)(base + 31457280);
  char* pB = base + 47185920;
  ushort_t* WU     = (ushort_t*)pB;  pB += 2359296;   // [2][18][64][64][8]
  ushort_t* slWt   = (ushort_t*)pB;  pB += 2097152;
  ushort_t* slUt   = (ushort_t*)pB;  pB += 1048576;
  ushort_t* m2Wt   = (ushort_t*)pB;  pB += 4194304;
  ushort_t* m2Ut   = (ushort_t*)pB;  pB += 1048576;
  float*    maxacc = (float*)pB;     pB += 3145728;   // [1536][512]
  ushort_t* pooledb= (ushort_t*)pB;  pB += 1572864;   // [1536][512] bf16
  ushort_t* hbuf1  = (ushort_t*)pB;  pB += 32768;
  ushort_t* hbuf2  = (ushort_t*)pB;  pB += 32768;
  unsigned* flags1 = (unsigned*)pB;  pB += 6144;      // v1 uses first [2][96]
  unsigned* flags2 = (unsigned*)pB;  pB += 6144;
  const int ZERO_N = (32768+32768+6144+6144)/4;
  // phased-hoist state (7.86 MB) + Gxw slices (2 x L x 6.29 MB f32)
  float*    cstS = (float*)pB;  pB += 3145728;        // [96][512][16]
  float*    mvvS = (float*)pB;  pB += 3145728;        // [96][512][16]
  ushort_t* hstS = (ushort_t*)pB; pB += 1572864;      // [96][32][256]
  const size_t PERT = 6291456ull;                     // bytes per t per dir (f32 gates)
  size_t off = (size_t)(pB - base);
  int Lsel = 0;
  const int cand[5] = {48, 24, 12, 8, 4};
  for (int ci = 0; ci < 5; ci++){
    size_t need = 2ull * (size_t)cand[ci] * PERT;
    if (off + need <= ws_size){ Lsel = cand[ci]; break; }
  }
  float* gxwA = (float*)(base + off);
  float* gxwB = (float*)(base + off + (size_t)Lsel*PERT);

  // ---- conversions + sync arena zero ----
  k_zero   <<<(ZERO_N+127)/128, 128, 0, stream>>>((unsigned*)hbuf1, ZERO_N);
  k_cvt_x  <<<11520, 256, 0, stream>>>(x, xT);
  k_cvt_wu <<<576,   256, 0, stream>>>(wl_Wf, wl_Uf, wl_Wb, wl_Ub, WU);
  k_cvt_gen<<<512,   256, 0, stream>>>(sl_Wf, sl_Wb, slWt, DD);
  k_cvt_gen<<<256,   256, 0, stream>>>(sl_Uf, sl_Ub, slUt, HH);
  k_cvt_gen<<<1024,  256, 0, stream>>>(m2_Wf, m2_Wb, m2Wt, GG);
  k_cvt_gen<<<256,   256, 0, stream>>>(m2_Uf, m2_Ub, m2Ut, HH);

  // ---- word-level: time-sliced gates_x hoist + U-only recurrence (or fallback) ----
  if (Lsel > 0){
    const int NPH = WW / Lsel;
    for (int ph = 0; ph < NPH; ph++){
      k_gxw<<<dim3(96, Lsel/4, 4), 512, 0, stream>>>(xT, WU, wl_bf, wl_bb, gxwA, gxwB, Lsel, ph);
      k_word_u_phase<<<96, 512, 0, stream>>>(gxwA, gxwB, WU, maxacc, slen,
                                             cstS, mvvS, hstS, Lsel, ph, NPH);
    }
  } else {
    k_word_persist_full<<<96, 512, 0, stream>>>(xT, WU, wl_bf, wl_bb, maxacc, slen);
  }
  k_pool_maskb<<<(NSEQ*DD)/256, 256, 0, stream>>>(maxacc, pooledb, dl);

  // ---- sentence LSTM 1 (parallel, 16 blocks, v1 sync) ----
  k_gemm_bf<<<dim3(24,8,2), 256, 0, stream>>>(pooledb, slWt, sl_bf, sl_bb, Gx1, DD);
  k_sstep_par<<<16, 128, 0, stream>>>(Gx1, slUt, hs, hbuf1, flags1, dl, 1);

  // ---- restricted attention ----
  k_attn<<<NSEQ, 256, 0, stream>>>(hs, attw, attb, dl, hrb);

  // ---- sentence LSTM 2 (parallel, 16 blocks, v1 sync) ----
  k_gemm_bf<<<dim3(24,8,2), 256, 0, stream>>>(hrb, m2Wt, m2_bf, m2_bb, Gx2, GG);
  k_sstep_par<<<16, 128, 0, stream>>>(Gx2, m2Ut, h2, hbuf2, flags2, dl, 0);

  // ---- classifier ----
  k_cls<<<NSEQ/4, 256, 0, stream>>>(h2, clsW, clsb, out);
}

// Round 10
// 2074.144 us; speedup vs baseline: 1.3562x; 1.0814x over previous
//
#include <hip/hip_runtime.h>
#include <math.h>

#define BB 16
#define SS 96
#define WW 48
#define EE 300
#define HH 256
#define GG 1024   // 4H
#define DD 512    // 2H
#define NSEQ 1536 // B*S
#define NKCW 18   // word chunks: 10 x-chunks (K=320 padded) + 8 h-chunks (K=256)

typedef __attribute__((ext_vector_type(8))) short bf16x8;
typedef __attribute__((ext_vector_type(4))) float f32x4;
typedef __attribute__((ext_vector_type(4))) _Float16 f16x4;
typedef unsigned short ushort_t;

__device__ __forceinline__ float sigf(float v){ return 1.0f/(1.0f+__expf(-v)); }
__device__ __forceinline__ float tanhf_fast(float v){ return 1.0f - 2.0f/(__expf(2.0f*v)+1.0f); }

__device__ __forceinline__ unsigned short f2bf(float f){
  union { float f; unsigned u; } v; v.f = f;
  unsigned u = v.u;
  u += 0x7FFFu + ((u>>16)&1u);   // RNE
  return (unsigned short)(u>>16);
}

// ============ conversions into MFMA-lane-linear layouts ============
// xT[grp 96][t 48][kc 10][lane 64][8]
// R9 edit: LDS-staged transpose. Old version read x with 16 lanes striding
// 57.6 KB (<=32B useful per 128B line, ~3-4x overfetch of a 101 MB input).
// New: one block per (grp,t); coalesced row reads -> LDS -> coalesced xT
// writes. Same values through the same f2bf -> output bit-identical.
__global__ __launch_bounds__(256) void k_cvt_x(const float* __restrict__ x, ushort_t* __restrict__ xT){
  const int grp = blockIdx.x / 48;
  const int t   = blockIdx.x % 48;
  const int tid = threadIdx.x;
  __shared__ float lds[16][304];
  for (int o = tid; o < 16*304; o += 256){
    int r = o / 304, e = o % 304;
    lds[r][e] = (e < EE) ? x[((size_t)(grp*16+r)*WW + t)*EE + e] : 0.f;
  }
  __syncthreads();
  ushort_t* dst = xT + (size_t)blockIdx.x*10*512;   // (grp*48+t)*5120
  for (int o = tid; o < 5120; o += 256){
    int d = o & 7, l = (o >> 3) & 63;
    int kc = o >> 9;
    int e = kc*32 + (l>>4)*8 + d;
    dst[o] = (e < EE) ? f2bf(lds[l & 15][e]) : 0;
  }
}

// WU[dir][kc 18][nt 64][lane 64][8]: kc<10 from W (K=320 pad of 300), kc>=10 from U (K=256)
__global__ __launch_bounds__(256) void k_cvt_wu(
    const float* __restrict__ Wf, const float* __restrict__ Uf,
    const float* __restrict__ Wb_, const float* __restrict__ Ub_,
    ushort_t* __restrict__ WU){
  int i = blockIdx.x*256 + threadIdx.x;        // 2*18*64*64 groups
  int l = i & 63;
  int nt = (i >> 6) & 63;
  int kc = (i >> 12) % NKCW;
  int dir = i / (NKCW*4096);
  int n = nt*16 + (l & 15);
  int lq8 = (l >> 4)*8;
  ushort_t* dst = WU + (size_t)i*8;
  if (kc < 10){
    int e = kc*32 + lq8;
    const float* src = (dir ? Wb_ : Wf) + (size_t)n*EE + e;
    #pragma unroll
    for (int d=0; d<8; d++) dst[d] = (e+d < EE) ? f2bf(src[d]) : 0;
  } else {
    int e = (kc-10)*32 + lq8;
    const float* src = (dir ? Ub_ : Uf) + (size_t)n*HH + e;
    #pragma unroll
    for (int d=0; d<8; d++) dst[d] = f2bf(src[d]);
  }
}

// Bt[dir][kc K/32][nt 64][lane 64][8] from row-major [1024][K] (per dir)
__global__ __launch_bounds__(256) void k_cvt_gen(
    const float* __restrict__ A0, const float* __restrict__ A1,
    ushort_t* __restrict__ Bt, int K){
  int i = blockIdx.x*256 + threadIdx.x;        // 2*(K/32)*64*64 groups
  int l = i & 63;
  int nt = (i >> 6) & 63;
  int nk = K >> 5;
  int kc = (i >> 12) % nk;
  int dir = i / (nk*4096);
  int n = nt*16 + (l & 15);
  int e = kc*32 + (l >> 4)*8;
  const float* src = (dir ? A1 : A0) + (size_t)n*K + e;
  ushort_t* dst = Bt + (size_t)i*8;
  #pragma unroll
  for (int d=0; d<8; d++) dst[d] = f2bf(src[d]);
}

// zero the sync/exchange arena
__global__ __launch_bounds__(128) void k_zero(unsigned* __restrict__ p, int n){
  int i = blockIdx.x*128 + threadIdx.x;
  if (i < n) p[i] = 0u;
}

// ============ pre-GEMM: gates_x for the word level, TIME-SLICED, f16 ============
// R9 edit: Gxw stored as f16 (halves PERT 6.29->3.15 MB/t/dir). Gate
// pre-activations |g| <~ 5 (x~N(0,1), W~0.05, K=300 => sigma~0.9): f16
// rounding (~5e-4) -> h error ~1e-4, an order below the bf16-h rounding
// (4e-3) already in the pipeline. Enables Lsel 4 -> 8/12 in the same
// workspace: halves phase count, save/restores, and Gxw HBM traffic.
__global__ __launch_bounds__(512) void k_gxw(
    const ushort_t* __restrict__ xT,   // [96][48][10][64][8]
    const ushort_t* __restrict__ WU,   // [2][18][64][64][8] (kc<10 = W-part)
    const float* __restrict__ bf_, const float* __restrict__ bb_,
    float* __restrict__ gxwA, float* __restrict__ gxwB,
    int L, int ph)
{
  const int grp = blockIdx.x;
  const int t0l = blockIdx.y*4;        // local t within slice
  const int dir = blockIdx.z >> 1;
  const int jh  = blockIdx.z & 1;
  const int tid = threadIdx.x;
  const int ng = tid >> 6, lane = tid & 63;
  const int lm = lane & 15, lq = lane >> 4;
  const int jt = jh*8 + ng;            // 0..15
  const int jc = jt*16 + lm;           // 0..255

  const int tbase = dir ? (WW - (ph+1)*L) : (ph*L);   // global t = tbase + t0l + tt
  float* GxS = dir ? gxwB : gxwA;

  const ushort_t* WUD = WU + (size_t)dir*NKCW*4096*8;
  const float* bias = dir ? bb_ : bf_;
  float bias_v[4];
  #pragma unroll
  for (int g=0; g<4; g++) bias_v[g] = bias[g*256 + jc];

  const ushort_t* xg = xT + ((size_t)grp*48 + (tbase + t0l))*10*512;

  bf16x8 curB[4], nxtB[4], curA[4], nxtA[4];
  #pragma unroll
  for (int g=0; g<4; g++)
    curB[g] = *(const bf16x8*)(WUD + ((size_t)(g*16 + jt)*64 + lane)*8);
  #pragma unroll
  for (int tt=0; tt<4; tt++)
    curA[tt] = *(const bf16x8*)(xg + (size_t)tt*10*512 + lane*8);

  f32x4 acc[4][4];
  #pragma unroll
  for (int tt=0; tt<4; tt++)
    #pragma unroll
    for (int g=0; g<4; g++){ acc[tt][g][0]=0.f; acc[tt][g][1]=0.f; acc[tt][g][2]=0.f; acc[tt][g][3]=0.f; }

  #pragma unroll
  for (int kc=0; kc<10; kc++){
    if (kc < 9){
      const int k1 = kc+1;
      #pragma unroll
      for (int g=0; g<4; g++)
        nxtB[g] = *(const bf16x8*)(WUD + ((size_t)k1*4096 + (g*16 + jt)*64 + lane)*8);
      #pragma unroll
      for (int tt=0; tt<4; tt++)
        nxtA[tt] = *(const bf16x8*)(xg + (size_t)tt*10*512 + k1*512 + lane*8);
    }
    #pragma unroll
    for (int tt=0; tt<4; tt++)
      #pragma unroll
      for (int g=0; g<4; g++)
        acc[tt][g] = __builtin_amdgcn_mfma_f32_16x16x32_bf16(curA[tt], curB[g], acc[tt][g], 0,0,0);
    #pragma unroll
    for (int g=0; g<4; g++) curB[g] = nxtB[g];
    #pragma unroll
    for (int tt=0; tt<4; tt++) curA[tt] = nxtA[tt];
  }

  f16x4* GxV = (f16x4*)GxS;
  #pragma unroll
  for (int tt=0; tt<4; tt++)
    #pragma unroll
    for (int r=0; r<4; r++){
      f16x4 v;
      v[0] = (_Float16)(acc[tt][0][r] + bias_v[0]);
      v[1] = (_Float16)(acc[tt][1][r] + bias_v[1]);
      v[2] = (_Float16)(acc[tt][2][r] + bias_v[2]);
      v[3] = (_Float16)(acc[tt][3][r] + bias_v[3]);
      GxV[(((size_t)grp*L + (t0l+tt))*16 + lq*4 + r)*256 + jc] = v;
    }
}

// ============ word-level recurrent BiLSTM, U-only, PHASED ============
// Gxw reads (f16x4) hoisted to the TOP of each step (h-independent) so their
// HBM latency hides under the MFMA chain.
__global__ __launch_bounds__(512) void k_word_u_phase(
    const float* __restrict__ gxwA, const float* __restrict__ gxwB,
    const ushort_t* __restrict__ WU,   // U chunks at [dir][10..17][..]
    float* __restrict__ maxacc,        // [1536][512]
    const int* __restrict__ slen,
    float* __restrict__ cstS,          // [96][512][16]
    float* __restrict__ mvvS,          // [96][512][16]
    ushort_t* __restrict__ hstS,       // [96][32][256]
    int L, int ph, int NPH)
{
  const int id = blockIdx.x;
  const int xcd = id & 7;
  const int dir = xcd & 1;
  const int bx = (xcd >> 1)*12 + (id >> 3);
  const int tid = threadIdx.x;
  const int ng = tid >> 6, lane = tid & 63;
  const int lm = lane & 15, lq = lane >> 4;
  const int jt0 = ng*32;

  __shared__ __align__(16) ushort_t hlds[2][32][264];
  for (int i = tid; i < 2*32*264/2; i += 512) ((unsigned*)hlds)[i] = 0u;
  __syncthreads();

  const ushort_t* UD = WU + (size_t)dir*NKCW*4096*8 + (size_t)10*4096*8;
  int ntb[4][2];
  #pragma unroll
  for (int g=0; g<4; g++)
    #pragma unroll
    for (int jt=0; jt<2; jt++) ntb[g][jt] = g*16 + ng*2 + jt;

  int slen_v[2][4];
  #pragma unroll
  for (int mh=0; mh<2; mh++)
    #pragma unroll
    for (int r=0; r<4; r++) slen_v[mh][r] = slen[bx*32 + mh*16 + lq*4 + r];

  float cst[2][2][4], mvv[2][2][4];
  if (ph == 0){
    #pragma unroll
    for (int mh=0; mh<2; mh++)
      #pragma unroll
      for (int jt=0; jt<2; jt++)
        #pragma unroll
        for (int r=0; r<4; r++){ cst[mh][jt][r]=0.f; mvv[mh][jt][r]=-1e30f; }
  } else {
    const float* cb = cstS + ((size_t)id*512 + tid)*16;
    const float* mb = mvvS + ((size_t)id*512 + tid)*16;
    #pragma unroll
    for (int mh=0; mh<2; mh++)
      #pragma unroll
      for (int jt=0; jt<2; jt++)
        #pragma unroll
        for (int r=0; r<4; r++){ cst[mh][jt][r]=cb[mh*8+jt*4+r]; mvv[mh][jt][r]=mb[mh*8+jt*4+r]; }
    const unsigned long long* hs = (const unsigned long long*)(hstS + (size_t)id*32*256);
    for (int i = tid; i < 2048; i += 512){
      int row = i >> 6, c8 = i & 63;
      *(unsigned long long*)&hlds[0][row][c8*4] = hs[i];
    }
  }

  const f16x4* GxS = (const f16x4*)(dir ? gxwB : gxwA);

  __syncthreads();
  int p = 0;

  for (int step=0; step<L; step++){
    const int t  = dir ? (WW-1 - ph*L - step) : (ph*L + step);   // global timestep
    const int tl = dir ? (L-1-step) : step;                      // local slice index

    // gates_x loads issued FIRST (h-independent) — hide under the MFMA chain
    f16x4 gxv[2][2][4];
    #pragma unroll
    for (int mh=0; mh<2; mh++)
      #pragma unroll
      for (int jt=0; jt<2; jt++)
        #pragma unroll
        for (int r=0; r<4; r++)
          gxv[mh][jt][r] = GxS[(((size_t)(bx*2+mh)*L + tl)*16 + lq*4 + r)*256 + jt0 + jt*16 + lm];

    bf16x8 curB[4][2], nxtB[4][2];
    bf16x8 curA0, curA1, nxtA0, nxtA1;
    #pragma unroll
    for (int g=0; g<4; g++)
      #pragma unroll
      for (int jt=0; jt<2; jt++)
        curB[g][jt] = *(const bf16x8*)(UD + ((size_t)ntb[g][jt]*64 + lane)*8);
    curA0 = *(const bf16x8*)&hlds[p][lm][lq*8];
    curA1 = *(const bf16x8*)&hlds[p][16+lm][lq*8];

    f32x4 acc[2][4][2];
    #pragma unroll
    for (int mh=0; mh<2; mh++)
      #pragma unroll
      for (int g=0; g<4; g++)
        #pragma unroll
        for (int jt=0; jt<2; jt++){ acc[mh][g][jt][0]=0.f; acc[mh][g][jt][1]=0.f; acc[mh][g][jt][2]=0.f; acc[mh][g][jt][3]=0.f; }

    #pragma unroll
    for (int kc=0; kc<8; kc++){
      if (kc < 7){
        const int k1 = kc+1;
        #pragma unroll
        for (int g=0; g<4; g++)
          #pragma unroll
          for (int jt=0; jt<2; jt++)
            nxtB[g][jt] = *(const bf16x8*)(UD + ((size_t)k1*4096 + ntb[g][jt]*64 + lane)*8);
        const int ko = k1*32 + lq*8;
        nxtA0 = *(const bf16x8*)&hlds[p][lm][ko];
        nxtA1 = *(const bf16x8*)&hlds[p][16+lm][ko];
      }
      #pragma unroll
      for (int g=0; g<4; g++)
        #pragma unroll
        for (int jt=0; jt<2; jt++){
          acc[0][g][jt] = __builtin_amdgcn_mfma_f32_16x16x32_bf16(curA0, curB[g][jt], acc[0][g][jt], 0,0,0);
          acc[1][g][jt] = __builtin_amdgcn_mfma_f32_16x16x32_bf16(curA1, curB[g][jt], acc[1][g][jt], 0,0,0);
        }
      #pragma unroll
      for (int g=0; g<4; g++)
        #pragma unroll
        for (int jt=0; jt<2; jt++) curB[g][jt] = nxtB[g][jt];
      curA0 = nxtA0; curA1 = nxtA1;
    }

    #pragma unroll
    for (int mh=0; mh<2; mh++)
      #pragma unroll
      for (int jt=0; jt<2; jt++)
        #pragma unroll
        for (int r=0; r<4; r++){
          float i_ = acc[mh][0][jt][r] + (float)gxv[mh][jt][r][0];
          float f_ = acc[mh][1][jt][r] + (float)gxv[mh][jt][r][1];
          float g_ = acc[mh][2][jt][r] + (float)gxv[mh][jt][r][2];
          float o_ = acc[mh][3][jt][r] + (float)gxv[mh][jt][r][3];
          float cn = sigf(f_)*cst[mh][jt][r] + sigf(i_)*tanhf_fast(g_);
          float hn = sigf(o_)*tanhf_fast(cn);
          cst[mh][jt][r] = cn;
          if (t < slen_v[mh][r]) mvv[mh][jt][r] = fmaxf(mvv[mh][jt][r], hn);
          hlds[1-p][mh*16 + lq*4 + r][jt0 + jt*16 + lm] = f2bf(hn);
        }
    __syncthreads();
    p ^= 1;
  }

  if (ph < NPH-1){
    float* cb = cstS + ((size_t)id*512 + tid)*16;
    float* mb = mvvS + ((size_t)id*512 + tid)*16;
    #pragma unroll
    for (int mh=0; mh<2; mh++)
      #pragma unroll
      for (int jt=0; jt<2; jt++)
        #pragma unroll
        for (int r=0; r<4; r++){ cb[mh*8+jt*4+r]=cst[mh][jt][r]; mb[mh*8+jt*4+r]=mvv[mh][jt][r]; }
    unsigned long long* hsv = (unsigned long long*)(hstS + (size_t)id*32*256);
    for (int i = tid; i < 2048; i += 512){
      int row = i >> 6, c8 = i & 63;
      hsv[i] = *(const unsigned long long*)&hlds[0][row][c8*4];
    }
  } else {
    #pragma unroll
    for (int mh=0; mh<2; mh++)
      #pragma unroll
      for (int jt=0; jt<2; jt++)
        #pragma unroll
        for (int r=0; r<4; r++)
          maxacc[(size_t)(bx*32 + mh*16 + lq*4 + r)*DD + dir*HH + jt0 + jt*16 + lm] = mvv[mh][jt][r];
  }
}

// ============ word-level persistent BiLSTM — FALLBACK (ws too small) ============
__global__ __launch_bounds__(512) __attribute__((amdgpu_waves_per_eu(2, 2))) void k_word_persist_full(
    const ushort_t* __restrict__ xT,
    const ushort_t* __restrict__ WU,
    const float* __restrict__ bf_, const float* __restrict__ bb_,
    float* __restrict__ maxacc,
    const int* __restrict__ slen)
{
  const int id = blockIdx.x;
  const int xcd = id & 7;
  const int dir = xcd & 1;
  const int bx = (xcd >> 1)*12 + (id >> 3);
  const int tid = threadIdx.x;
  const int ng = tid >> 6, lane = tid & 63;
  const int lm = lane & 15, lq = lane >> 4;
  const int jt0 = ng*32;

  __shared__ __align__(16) ushort_t hlds[2][32][264];
  for (int i = tid; i < 2*32*264/2; i += 512) ((unsigned*)hlds)[i] = 0u;

  const ushort_t* WUD = WU + (size_t)dir*NKCW*4096*8;
  int ntb[4][2];
  #pragma unroll
  for (int g=0; g<4; g++)
    #pragma unroll
    for (int jt=0; jt<2; jt++) ntb[g][jt] = g*16 + ng*2 + jt;

  const float* bias = dir ? bb_ : bf_;
  float bias_v[4][2];
  #pragma unroll
  for (int g=0; g<4; g++)
    #pragma unroll
    for (int jt=0; jt<2; jt++) bias_v[g][jt] = bias[g*256 + jt0 + jt*16 + lm];

  int slen_v[2][4];
  #pragma unroll
  for (int mh=0; mh<2; mh++)
    #pragma unroll
    for (int r=0; r<4; r++) slen_v[mh][r] = slen[bx*32 + mh*16 + lq*4 + r];

  float cst[2][2][4], mvv[2][2][4];
  #pragma unroll
  for (int mh=0; mh<2; mh++)
    #pragma unroll
    for (int jt=0; jt<2; jt++)
      #pragma unroll
      for (int r=0; r<4; r++){ cst[mh][jt][r]=0.f; mvv[mh][jt][r]=-1e30f; }

  const ushort_t* xg0 = xT + (size_t)(bx*2+0)*48*10*512;
  const ushort_t* xg1 = xT + (size_t)(bx*2+1)*48*10*512;

  __syncthreads();
  int p = 0;

  for (int step=0; step<WW; step++){
    const int t = dir ? (WW-1-step) : step;
    const size_t xoff = (size_t)t*10*512 + lane*8;

    bf16x8 curB[4][2], nxtB[4][2];
    bf16x8 curA0, curA1, nxtA0, nxtA1;
    #pragma unroll
    for (int g=0; g<4; g++)
      #pragma unroll
      for (int jt=0; jt<2; jt++)
        curB[g][jt] = *(const bf16x8*)(WUD + ((size_t)ntb[g][jt]*64 + lane)*8);
    curA0 = *(const bf16x8*)(xg0 + xoff);
    curA1 = *(const bf16x8*)(xg1 + xoff);

    f32x4 acc[2][4][2];
    #pragma unroll
    for (int mh=0; mh<2; mh++)
      #pragma unroll
      for (int g=0; g<4; g++)
        #pragma unroll
        for (int jt=0; jt<2; jt++){ acc[mh][g][jt][0]=0.f; acc[mh][g][jt][1]=0.f; acc[mh][g][jt][2]=0.f; acc[mh][g][jt][3]=0.f; }

    #pragma unroll
    for (int kc=0; kc<NKCW; kc++){
      if (kc < NKCW-1){
        const int k1 = kc+1;
        #pragma unroll
        for (int g=0; g<4; g++)
          #pragma unroll
          for (int jt=0; jt<2; jt++)
            nxtB[g][jt] = *(const bf16x8*)(WUD + ((size_t)k1*4096 + ntb[g][jt]*64 + lane)*8);
        if (k1 < 10){
          nxtA0 = *(const bf16x8*)(xg0 + xoff + k1*512);
          nxtA1 = *(const bf16x8*)(xg1 + xoff + k1*512);
        } else {
          const int ko = (k1-10)*32 + lq*8;
          nxtA0 = *(const bf16x8*)&hlds[p][lm][ko];
          nxtA1 = *(const bf16x8*)&hlds[p][16+lm][ko];
        }
      }
      #pragma unroll
      for (int g=0; g<4; g++)
        #pragma unroll
        for (int jt=0; jt<2; jt++){
          acc[0][g][jt] = __builtin_amdgcn_mfma_f32_16x16x32_bf16(curA0, curB[g][jt], acc[0][g][jt], 0,0,0);
          acc[1][g][jt] = __builtin_amdgcn_mfma_f32_16x16x32_bf16(curA1, curB[g][jt], acc[1][g][jt], 0,0,0);
        }
      #pragma unroll
      for (int g=0; g<4; g++)
        #pragma unroll
        for (int jt=0; jt<2; jt++) curB[g][jt] = nxtB[g][jt];
      curA0 = nxtA0; curA1 = nxtA1;
    }

    #pragma unroll
    for (int mh=0; mh<2; mh++)
      #pragma unroll
      for (int jt=0; jt<2; jt++)
        #pragma unroll
        for (int r=0; r<4; r++){
          float i_ = acc[mh][0][jt][r] + bias_v[0][jt];
          float f_ = acc[mh][1][jt][r] + bias_v[1][jt];
          float g_ = acc[mh][2][jt][r] + bias_v[2][jt];
          float o_ = acc[mh][3][jt][r] + bias_v[3][jt];
          float cn = sigf(f_)*cst[mh][jt][r] + sigf(i_)*tanhf_fast(g_);
          float hn = sigf(o_)*tanhf_fast(cn);
          cst[mh][jt][r] = cn;
          if (t < slen_v[mh][r]) mvv[mh][jt][r] = fmaxf(mvv[mh][jt][r], hn);
          hlds[1-p][mh*16 + lq*4 + r][jt0 + jt*16 + lm] = f2bf(hn);
        }
    __syncthreads();
    p ^= 1;
  }
  #pragma unroll
  for (int mh=0; mh<2; mh++)
    #pragma unroll
    for (int jt=0; jt<2; jt++)
      #pragma unroll
      for (int r=0; r<4; r++)
        maxacc[(size_t)(bx*32 + mh*16 + lq*4 + r)*DD + dir*HH + jt0 + jt*16 + lm] = mvv[mh][jt][r];
}

// ============ maxpool mask -> bf16 pooled ============
__global__ __launch_bounds__(256) void k_pool_maskb(
    const float* __restrict__ maxacc, ushort_t* __restrict__ pooled_bf, const int* __restrict__ dl)
{
  int i = blockIdx.x*256 + threadIdx.x;       // NSEQ*DD
  int m = i / DD; int b = m / SS; int s = m % SS;
  pooled_bf[i] = (s < dl[b]) ? f2bf(maxacc[i]) : 0;
}

// ============ bf16 GEMM: C[z][1536xGG] = A[1536xK] @ B[z] + bias (B lane-linear) ============
__global__ __launch_bounds__(256) void k_gemm_bf(
    const ushort_t* __restrict__ A,
    const ushort_t* __restrict__ Bt,      // [2][K/32][64][64][8]
    const float* __restrict__ bias0, const float* __restrict__ bias1,
    float* __restrict__ C,                // [2][NSEQ][GG]
    int K)
{
  const int z = blockIdx.z;
  const int nk = K >> 5;
  const ushort_t* BD = Bt + (size_t)z*nk*4096*8;
  const float* bias = z ? bias1 : bias0;
  float* Cz = C + (size_t)z*NSEQ*GG;

  const int tid = threadIdx.x;
  const int w = tid >> 6, lane = tid & 63;
  const int lm = lane & 15, lq = lane >> 4;
  const int m0 = blockIdx.x*64 + w*16, nt0 = blockIdx.y*8;

  const ushort_t* arow = A + (size_t)(m0+lm)*K + lq*8;

  f32x4 acc[8];
  #pragma unroll
  for (int j=0; j<8; j++){ acc[j][0]=0.f; acc[j][1]=0.f; acc[j][2]=0.f; acc[j][3]=0.f; }

  #pragma unroll 4
  for (int kc=0; kc<nk; kc++){
    bf16x8 a = *(const bf16x8*)(arow + kc*32);
    #pragma unroll
    for (int j=0; j<8; j++){
      bf16x8 b = *(const bf16x8*)(BD + ((size_t)kc*4096 + (nt0+j)*64 + lane)*8);
      acc[j] = __builtin_amdgcn_mfma_f32_16x16x32_bf16(a, b, acc[j], 0,0,0);
    }
  }
  #pragma unroll
  for (int j=0; j<8; j++){
    int n = (nt0+j)*16 + lm;
    float bv = bias[n];
    #pragma unroll
    for (int r=0; r<4; r++)
      Cz[(size_t)(m0 + lq*4 + r)*GG + n] = acc[j][r] + bv;
  }
}

// ============ sentence-level LSTM, PARALLEL across 16 blocks — v1 sync ============
// Empirical floor for this structure (R6-R9: v1=397-406, v2=433, v3=670).
__global__ __launch_bounds__(128) void k_sstep_par(
    const float* __restrict__ Gx,     // [2][1536][1024], bias included
    const ushort_t* __restrict__ Ut,  // [2][8][64][64][8]
    float* __restrict__ outseq,       // [16][96][512]
    ushort_t* __restrict__ hbuf,      // [2 parity][2 dir][16 doc][256] bf16, pre-zeroed
    unsigned* __restrict__ flags,     // [2 dir][96], pre-zeroed
    const int* __restrict__ dl, int mask_out)
{
  const int dir = blockIdx.x >> 3;
  const int ns  = blockIdx.x & 7;
  const int tid = threadIdx.x;
  const int jt  = tid >> 6;
  const int lane = tid & 63, lm = lane & 15, lq = lane >> 4;

  __shared__ __align__(16) ushort_t Ul[8][4][2][64][8];   // 64 KB

  {
    const ushort_t* UD = Ut + (size_t)dir*8*4096*8;
    for (int v = tid; v < 4096; v += 128){
      int lane_v = v & 63;
      int q = v >> 6;
      int jv = q & 1, gq = (q >> 1) & 3, kcv = q >> 3;
      const uint4* src = (const uint4*)(UD + ((size_t)kcv*4096 + (gq*16 + ns*2 + jv)*64 + lane_v)*8);
      ((uint4*)Ul)[v] = *src;
    }
  }

  int dl_v[4];
  #pragma unroll
  for (int r=0; r<4; r++) dl_v[r] = dl[lq*4 + r];

  float cst[4];
  #pragma unroll
  for (int r=0; r<4; r++) cst[r] = 0.f;

  unsigned* flg = flags + dir*SS;
  const float* GxD = Gx + (size_t)dir*NSEQ*GG;
  ushort_t* hb0 = hbuf + (size_t)dir*16*256;
  ushort_t* hb1 = hbuf + (size_t)(2+dir)*16*256;
  const int j = ns*32 + jt*16 + lm;

  __syncthreads();
  int p = 0;

  for (int step=0; step<SS; step++){
    const int t = dir ? (SS-1-step) : step;

    if (step > 0){
      if (tid == 0){
        while (__hip_atomic_load(&flg[step-1], __ATOMIC_ACQUIRE, __HIP_MEMORY_SCOPE_AGENT) < 8u) {}
      }
      __syncthreads();
    }
    ushort_t* hcur = p ? hb1 : hb0;
    ushort_t* hnxt = p ? hb0 : hb1;

    unsigned long long av[8][2];
    #pragma unroll
    for (int kc=0; kc<8; kc++){
      unsigned long long* src = (unsigned long long*)(hcur + (size_t)lm*256 + kc*32 + lq*8);
      av[kc][0] = __hip_atomic_load(&src[0], __ATOMIC_RELAXED, __HIP_MEMORY_SCOPE_AGENT);
      av[kc][1] = __hip_atomic_load(&src[1], __ATOMIC_RELAXED, __HIP_MEMORY_SCOPE_AGENT);
    }

    float gx[4][4];
    #pragma unroll
    for (int g=0; g<4; g++)
      #pragma unroll
      for (int r=0; r<4; r++)
        gx[g][r] = GxD[((size_t)(lq*4+r)*SS + t)*GG + g*256 + j];

    f32x4 acc[4];
    #pragma unroll
    for (int g=0; g<4; g++){ acc[g][0]=0.f; acc[g][1]=0.f; acc[g][2]=0.f; acc[g][3]=0.f; }

    #pragma unroll
    for (int kc=0; kc<8; kc++){
      union { unsigned long long u[2]; bf16x8 v; } au;
      au.u[0] = av[kc][0]; au.u[1] = av[kc][1];
      bf16x8 a = au.v;
      #pragma unroll
      for (int g=0; g<4; g++){
        bf16x8 b = *(const bf16x8*)&Ul[kc][g][jt][lane][0];
        acc[g] = __builtin_amdgcn_mfma_f32_16x16x32_bf16(a, b, acc[g], 0,0,0);
      }
    }

    #pragma unroll
    for (int r=0; r<4; r++){
      const int doc = lq*4 + r;
      float i_ = acc[0][r] + gx[0][r];
      float f_ = acc[1][r] + gx[1][r];
      float g_ = acc[2][r] + gx[2][r];
      float o_ = acc[3][r] + gx[3][r];
      float cn = sigf(f_)*cst[r] + sigf(i_)*tanhf_fast(g_);
      float hn = sigf(o_)*tanhf_fast(cn);
      cst[r] = cn;
      __hip_atomic_store(&hnxt[(size_t)doc*256 + j], (ushort_t)f2bf(hn),
                         __ATOMIC_RELAXED, __HIP_MEMORY_SCOPE_AGENT);
      float ho = hn;
      if (mask_out && t >= dl_v[r]) ho = 0.f;
      outseq[((size_t)doc*SS + t)*DD + dir*HH + j] = ho;
    }

    __threadfence();
    __syncthreads();
    if (tid == 0)
      __hip_atomic_fetch_add(&flg[step], 1u, __ATOMIC_RELEASE, __HIP_MEMORY_SCOPE_AGENT);
    p ^= 1;
  }
}

// ============ restricted attention (bf16 output for next GEMM) ============
__global__ __launch_bounds__(256) void k_attn(
    const float* __restrict__ X, const float* __restrict__ aw_,
    const float* __restrict__ ab_, const int* __restrict__ dl, ushort_t* __restrict__ hr)
{
  const int bs = blockIdx.x, b = bs / SS, s = bs % SS, tid = threadIdx.x;
  const float* xc = X + (size_t)bs*DD;
  ushort_t* outp = hr + (size_t)bs*(2*DD);
  for (int d=tid; d<DD; d+=256) outp[d] = f2bf(xc[d]);
  const int dlb = dl[b];
  if (s >= dlb){
    for (int d=tid; d<DD; d+=256) outp[DD+d] = 0;
    return;
  }
  __shared__ float xw[7][DD];
  __shared__ float red4[4][23];
  __shared__ float redm[23];
  for (int k=0;k<7;k++){
    int idx = s-3+k; idx = idx < 0 ? 0 : (idx > SS-1 ? SS-1 : idx);
    const float* row = X + ((size_t)b*SS + idx)*DD;
    for (int d=tid; d<DD; d+=256) xw[k][d] = row[d];
  }
  __syncthreads();
  float pv[23];
  #pragma unroll
  for (int i=0;i<23;i++) pv[i] = 0.f;
  #pragma unroll
  for (int pass=0; pass<2; pass++){
    int d = tid + pass*256;
    float xv = xc[d];
    pv[0] += xv*xv;
    pv[1] += xv * aw_[DD + d];
    float w1 = aw_[d];
    #pragma unroll
    for (int k=0;k<7;k++){
      float wv = xw[k][d];
      pv[2+3*k] += wv*xv;
      pv[3+3*k] += wv*wv;
      pv[4+3*k] += wv*w1;
    }
  }
  const int lane = tid & 63, wid = tid >> 6;
  #pragma unroll
  for (int i=0;i<23;i++){
    float v = pv[i];
    for (int o=32;o>0;o>>=1) v += __shfl_down(v, o, 64);
    if (lane==0) red4[wid][i] = v;
  }
  __syncthreads();
  if (tid < 23) redm[tid] = red4[0][tid]+red4[1][tid]+red4[2][tid]+red4[3][tid];
  __syncthreads();
  float nc = fmaxf(sqrtf(redm[0]), 1e-12f);
  float cterm = redm[1] + ab_[0];
  float wsim = aw_[2*DD];
  float sck[7]; float mx = -1e30f;
  #pragma unroll
  for (int k=0;k<7;k++){
    int idx = s-3+k;
    bool valid = (idx >= 0) && (idx < dlb);
    float nw = fmaxf(sqrtf(redm[3+3*k]), 1e-12f);
    float sim = sigf(redm[2+3*k] / (nw*nc));
    float sc = redm[4+3*k] + cterm + sim*wsim;
    sck[k] = valid ? sc : -1e30f;
    mx = fmaxf(mx, sck[k]);
  }
  float sum = 0.f;
  #pragma unroll
  for (int k=0;k<7;k++){ sck[k] = __expf(sck[k]-mx); sum += sck[k]; }
  float inv = 1.0f/sum;
  for (int d=tid; d<DD; d+=256){
    float cv = 0.f;
    #pragma unroll
    for (int k=0;k<7;k++) cv += sck[k]*xw[k][d];
    outp[DD+d] = f2bf(cv*inv);
  }
}

// ============ classifier + softmax ============
__global__ __launch_bounds__(256) void k_cls(
    const float* __restrict__ h2, const float* __restrict__ Wc,
    const float* __restrict__ bc, float* __restrict__ out)
{
  int pos = blockIdx.x*4 + (threadIdx.x >> 6);
  int lane = threadIdx.x & 63;
  const float* hv = h2 + (size_t)pos*DD;
  float a0 = 0.f, a1 = 0.f;
  for (int d=lane; d<DD; d+=64){ float h = hv[d]; a0 += h*Wc[d]; a1 += h*Wc[DD+d]; }
  for (int o=32;o>0;o>>=1){ a0 += __shfl_down(a0,o,64); a1 += __shfl_down(a1,o,64); }
  if (lane==0){
    float l0 = a0 + bc[0], l1 = a1 + bc[1];
    float m = fmaxf(l0,l1);
    float e0 = __expf(l0-m), e1 = __expf(l1-m);
    float s = e0+e1;
    out[pos*2]   = e0/s;
    out[pos*2+1] = e1/s;
  }
}

extern "C" void kernel_launch(void* const* d_in, const int* in_sizes, int n_in,
                              void* d_out, int out_size, void* d_ws, size_t ws_size,
                              hipStream_t stream) {
  const float* x    = (const float*)d_in[0];
  const int* slen   = (const int*)d_in[1];
  const int* dl     = (const int*)d_in[2];
  const float* wl_Wf=(const float*)d_in[3];
  const float* wl_Uf=(const float*)d_in[4];
  const float* wl_bf=(const float*)d_in[5];
  const float* wl_Wb=(const float*)d_in[6];
  const float* wl_Ub=(const float*)d_in[7];
  const float* wl_bb=(const float*)d_in[8];
  const float* sl_Wf=(const float*)d_in[9];
  const float* sl_Uf=(const float*)d_in[10];
  const float* sl_bf=(const float*)d_in[11];
  const float* sl_Wb=(const float*)d_in[12];
  const float* sl_Ub=(const float*)d_in[13];
  const float* sl_bb=(const float*)d_in[14];
  const float* attw =(const float*)d_in[15];
  const float* attb =(const float*)d_in[16];
  const float* m2_Wf=(const float*)d_in[17];
  const float* m2_Uf=(const float*)d_in[18];
  const float* m2_bf=(const float*)d_in[19];
  const float* m2_Wb=(const float*)d_in[20];
  const float* m2_Ub=(const float*)d_in[21];
  const float* m2_bb=(const float*)d_in[22];
  const float* clsW =(const float*)d_in[23];
  const float* clsb =(const float*)d_in[24];
  float* out = (float*)d_out;

  // ---- workspace layout (bytes) ----
  char* base = (char*)d_ws;
  ushort_t* xT  = (ushort_t*)base;                 // 47,185,920 (word phase)
  float* Gx1    = (float*)base;                    // reused after word phase
  float* Gx2    = (float*)(base + 12582912);
  ushort_t* hrb = (ushort_t*)(base + 25165824);
  float* hs     = (float*)(base + 28311552);
  float* h2     = (float*)(base + 31457280);
  char* pB = base + 47185920;
  ushort_t* WU     = (ushort_t*)pB;  pB += 2359296;   // [2][18][64][64][8]
  ushort_t* slWt   = (ushort_t*)pB;  pB += 2097152;
  ushort_t* slUt   = (ushort_t*)pB;  pB += 1048576;
  ushort_t* m2Wt   = (ushort_t*)pB;  pB += 4194304;
  ushort_t* m2Ut   = (ushort_t*)pB;  pB += 1048576;
  float*    maxacc = (float*)pB;     pB += 3145728;   // [1536][512]
  ushort_t* pooledb= (ushort_t*)pB;  pB += 1572864;   // [1536][512] bf16
  ushort_t* hbuf1  = (ushort_t*)pB;  pB += 32768;
  ushort_t* hbuf2  = (ushort_t*)pB;  pB += 32768;
  unsigned* flags1 = (unsigned*)pB;  pB += 6144;      // v1 uses first [2][96]
  unsigned* flags2 = (unsigned*)pB;  pB += 6144;
  const int ZERO_N = (32768+32768+6144+6144)/4;
  // phased-hoist state (7.86 MB) + Gxw slices (2 x L x 3.15 MB, f16)
  float*    cstS = (float*)pB;  pB += 3145728;        // [96][512][16]
  float*    mvvS = (float*)pB;  pB += 3145728;        // [96][512][16]
  ushort_t* hstS = (ushort_t*)pB; pB += 1572864;      // [96][32][256]
  const size_t PERT = 3145728ull;                     // bytes per t per dir (f16 gates)
  size_t off = (size_t)(pB - base);
  int Lsel = 0;
  const int cand[5] = {48, 24, 12, 8, 4};
  for (int ci = 0; ci < 5; ci++){
    size_t need = 2ull * (size_t)cand[ci] * PERT;
    if (off + need <= ws_size){ Lsel = cand[ci]; break; }
  }
  float* gxwA = (float*)(base + off);
  float* gxwB = (float*)(base + off + (size_t)Lsel*PERT);

  // ---- conversions + sync arena zero ----
  k_zero   <<<(ZERO_N+127)/128, 128, 0, stream>>>((unsigned*)hbuf1, ZERO_N);
  k_cvt_x  <<<4608,  256, 0, stream>>>(x, xT);
  k_cvt_wu <<<576,   256, 0, stream>>>(wl_Wf, wl_Uf, wl_Wb, wl_Ub, WU);
  k_cvt_gen<<<512,   256, 0, stream>>>(sl_Wf, sl_Wb, slWt, DD);
  k_cvt_gen<<<256,   256, 0, stream>>>(sl_Uf, sl_Ub, slUt, HH);
  k_cvt_gen<<<1024,  256, 0, stream>>>(m2_Wf, m2_Wb, m2Wt, GG);
  k_cvt_gen<<<256,   256, 0, stream>>>(m2_Uf, m2_Ub, m2Ut, HH);

  // ---- word-level: time-sliced gates_x hoist (f16 slices) + U-only recurrence ----
  if (Lsel > 0){
    const int NPH = WW / Lsel;
    for (int ph = 0; ph < NPH; ph++){
      k_gxw<<<dim3(96, Lsel/4, 4), 512, 0, stream>>>(xT, WU, wl_bf, wl_bb, gxwA, gxwB, Lsel, ph);
      k_word_u_phase<<<96, 512, 0, stream>>>(gxwA, gxwB, WU, maxacc, slen,
                                             cstS, mvvS, hstS, Lsel, ph, NPH);
    }
  } else {
    k_word_persist_full<<<96, 512, 0, stream>>>(xT, WU, wl_bf, wl_bb, maxacc, slen);
  }
  k_pool_maskb<<<(NSEQ*DD)/256, 256, 0, stream>>>(maxacc, pooledb, dl);

  // ---- sentence LSTM 1 (parallel, 16 blocks, v1 sync) ----
  k_gemm_bf<<<dim3(24,8,2), 256, 0, stream>>>(pooledb, slWt, sl_bf, sl_bb, Gx1, DD);
  k_sstep_par<<<16, 128, 0, stream>>>(Gx1, slUt, hs, hbuf1, flags1, dl, 1);

  // ---- restricted attention ----
  k_attn<<<NSEQ, 256, 0, stream>>>(hs, attw, attb, dl, hrb);

  // ---- sentence LSTM 2 (parallel, 16 blocks, v1 sync) ----
  k_gemm_bf<<<dim3(24,8,2), 256, 0, stream>>>(hrb, m2Wt, m2_bf, m2_bb, Gx2, GG);
  k_sstep_par<<<16, 128, 0, stream>>>(Gx2, m2Ut, h2, hbuf2, flags2, dl, 0);

  // ---- classifier ----
  k_cls<<<NSEQ/4, 256, 0, stream>>>(h2, clsW, clsb, out);
}